// Round 14
// baseline (6408.755 us; speedup 1.0000x reference)
//
#include <hip/hip_runtime.h>
#include <math.h>

typedef unsigned short u16;
typedef unsigned int u32;
typedef unsigned long long u64;
typedef __attribute__((ext_vector_type(8))) short short8v;
typedef __attribute__((ext_vector_type(4))) float f32x4;

static const int NN  = 16384;
static const int NE  = 524288;
static const int SCC = 1024;   // sim column chunk
static const int KEDGE = 17;

__device__ __forceinline__ u16 f2b(float v){
  u32 u = __float_as_uint(v);
  u += 0x7FFFu + ((u >> 16) & 1u);
  return (u16)(u >> 16);
}
__device__ __forceinline__ float b2f(u16 h){ return __uint_as_float(((u32)h) << 16); }

// async 16B global->LDS (gfx950). LDS dest is wave-uniform base + lane*16.
__device__ __forceinline__ void gl_lds16(const u16* g, u16* l){
  __builtin_amdgcn_global_load_lds(
      (const __attribute__((address_space(1))) u32*)(g),
      (__attribute__((address_space(3))) u32*)(l), 16, 0, 0);
}

// ---------------- utility ----------------
__global__ void k_fill_i32(int* p, int v, int n){
  int i = blockIdx.x*256 + threadIdx.x; if (i < n) p[i] = v;
}
// fp32 [n] (rows of C) -> h/m at [r*ldo+co+c], l (optional) at [r*ldl+c]
__global__ void k_split3(const float* __restrict__ s, u16* __restrict__ h,
                         u16* __restrict__ m, u16* __restrict__ l, int n,
                         int C, int ldo, int co, int ldl){
  int i = blockIdx.x*256 + threadIdx.x; if (i >= n) return;
  int r = i / C, c = i % C;
  float v = s[i];
  u16 hh = f2b(v);
  float rr = v - b2f(hh);
  u16 mm_ = f2b(rr);
  size_t o = (size_t)r*ldo + co + c;
  h[o] = hh; m[o] = mm_;
  if (l) l[(size_t)r*ldl + c] = f2b(rr - b2f(mm_));
}
// W [K,N] fp32 -> Wt [Npad,K] 3-way split, zero rows for n >= N
__global__ void k_wprep3(const float* __restrict__ W, int K, int N, int Npad,
                         u16* __restrict__ h, u16* __restrict__ m, u16* __restrict__ l){
  int idx = blockIdx.x*256 + threadIdx.x; if (idx >= K*Npad) return;
  int n = idx / K, k = idx % K;
  float v = (n < N) ? W[(size_t)k*N + n] : 0.f;
  u16 hh = f2b(v); h[idx] = hh;
  float r = v - b2f(hh);
  u16 mm_ = f2b(r); m[idx] = mm_;
  l[idx] = f2b(r - b2f(mm_));
}

// ---------------- CSR build ----------------
__global__ void k_hist(const int* __restrict__ dst, int* __restrict__ cnt){
  int e = blockIdx.x*256 + threadIdx.x; if (e < NE) atomicAdd(&cnt[dst[e]], 1);
}
__global__ void k_scan(const int* __restrict__ cnt, int* __restrict__ off){
  __shared__ int part[1024];
  int t = threadIdx.x;
  int base = t*16;
  int loc[16]; int s = 0;
#pragma unroll
  for (int q=0;q<16;q++){ loc[q] = s; s += cnt[base+q]; }
  part[t] = s; __syncthreads();
  for (int d=1; d<1024; d<<=1){
    int v = (t>=d) ? part[t-d] : 0; __syncthreads();
    part[t] += v; __syncthreads();
  }
  int prev = (t==0) ? 0 : part[t-1];
#pragma unroll
  for (int q=0;q<16;q++) off[base+q] = prev + loc[q];
  if (t == 1023) off[NN] = part[1023];
}
__global__ void k_csr_fill(const int* __restrict__ src, const int* __restrict__ dst,
                           const int* __restrict__ off, int* __restrict__ cur,
                           int* __restrict__ csrc, int* __restrict__ ceid){
  int e = blockIdx.x*256 + threadIdx.x; if (e >= NE) return;
  int d = dst[e];
  int p = atomicAdd(&cur[d], 1);
  int idx = off[d] + p;
  csrc[idx] = src[e];
  ceid[idx] = e;
}

// ---------------- static segment-max (fp32 in, split3 out) ----------------
__global__ void k_static_segmax(const float* __restrict__ x, int Dx,
                                const float* __restrict__ ea,
                                const int* __restrict__ off,
                                const int* __restrict__ csrc,
                                const int* __restrict__ ceid,
                                u16* __restrict__ th, u16* __restrict__ tm,
                                u16* __restrict__ tl){
  int i = blockIdx.x, c = threadIdx.x;
  int DM = Dx + 64;
  int s = off[i], e = off[i+1];
  float mx = -INFINITY;
  float v;
  if (c < Dx){
    for (int t = s; t < e; t++) mx = fmaxf(mx, x[(size_t)csrc[t]*Dx + c]);
    v = (s == e) ? 0.f : (mx - x[(size_t)i*Dx + c]);
  } else {
    int cc = c - Dx;
    for (int t = s; t < e; t++) mx = fmaxf(mx, ea[(size_t)ceid[t]*64 + cc]);
    v = (s == e) ? 0.f : mx;
  }
  size_t o = (size_t)i*DM + c;
  u16 h = f2b(v); th[o] = h;
  float r = v - b2f(h);
  u16 mm_ = f2b(r); tm[o] = mm_;
  tl[o] = f2b(r - b2f(mm_));
}

// ---------------- MFMA GEMM over 3-way splits (global_load_lds staging) -------
// Round-7 form + XCD-bijective block swizzle (all launch grids have nwg%8==0,
// so consecutive tiles land on the same XCD -> L2 panel reuse; perf-only).
template<int P, int GATHER>
__global__ __launch_bounds__(256) void k_mgemm(
    const u16* __restrict__ Ah, const u16* __restrict__ Am, const u16* __restrict__ Al,
    int lda, int ldal,
    const u16* __restrict__ Bh, const u16* __restrict__ Bm, const u16* __restrict__ Bl,
    int ldb,
    float* __restrict__ Cf, u16* __restrict__ Ch, u16* __restrict__ Cm, u16* __restrict__ Cl,
    int ldc, int ldsp, int cosp, int ldspl,
    int K, int Nc, float slope, int flags, int colbase,
    const float* __restrict__ Xf, const int* __restrict__ topig, int c0g, int Dxg)
{
  constexpr int NC = (P == 3) ? 3 : 2;
  __shared__ u16 lds[NC*2*4096];
  const int t = threadIdx.x;
  // XCD swizzle: bid -> (xcd chunk), bijective since nwg % 8 == 0
  const int nwgx = gridDim.x;
  const int bid = blockIdx.y * nwgx + blockIdx.x;
  const int cpx = (nwgx * gridDim.y) >> 3;
  const int swz = (bid & 7) * cpx + (bid >> 3);
  const int m0 = (swz / nwgx) * 128, n0 = (swz % nwgx) * 128;
  const int wave = t >> 6, lane = t & 63;
  const int wr = (wave >> 1) << 6, wc = (wave & 1) << 6;
  const int l15 = lane & 15, l4 = lane >> 4;
  f32x4 acc[4][4] = {};

  const u16* Ap[3] = {Ah, Am, Al};
  const int ldav[3] = {lda, lda, ldal};
  const u16* Bp[3] = {Bh, Bm, Bl};

  const int c0c = wave*128 + lane, c1c = c0c + 64;
  const int r0c = c0c & 127, s0c = c0c >> 7;
  const int r1c = c1c & 127, s1c = c1c >> 7;
  const int lb0 = (wave*128)*8;
  const int lb1 = (wave*128 + 64)*8;

  size_t gA0[3], gA1[3], gB0[3], gB1[3];
#pragma unroll
  for (int cc=0; cc<NC; cc++){
    if (!GATHER){
      gA0[cc] = (size_t)(m0 + r0c)*ldav[cc] + s0c*8;
      gA1[cc] = (size_t)(m0 + r1c)*ldav[cc] + s1c*8;
    }
    gB0[cc] = (size_t)(n0 + r0c)*ldb + s0c*8;
    gB1[cc] = (size_t)(n0 + r1c)*ldb + s1c*8;
  }

  const int sr = t & 127, sseg = t >> 7;
  int node_i = 0, node_j = 0;
  if (GATHER){
    int erow = m0 + sr;
    int i = c0g + erow / KEDGE;
    int slot = erow % KEDGE;
    node_i = i;
    node_j = (slot < 16) ? topig[i*16 + slot] : i;
  }

  for (int k0 = 0; k0 < K; k0 += 32){
    __attribute__((aligned(16))) u16 hb[16], mb[16], lcb[16];
    if (GATHER){
      int kpos = k0 + sseg*16;
      bool side = kpos < Dxg;
      int kk = side ? kpos : kpos - Dxg;
      const float* xi = Xf + (size_t)node_i*Dxg + kk;
      const float* xj = Xf + (size_t)node_j*Dxg + kk;
#pragma unroll
      for (int q4=0;q4<4;q4++){
        float4 a = *(const float4*)(xi + q4*4);
        if (!side){
          float4 b = *(const float4*)(xj + q4*4);
          a = make_float4(b.x-a.x, b.y-a.y, b.z-a.z, b.w-a.w);
        }
        float vv[4] = {a.x, a.y, a.z, a.w};
#pragma unroll
        for (int q=0;q<4;q++){
          float v = vv[q];
          u16 h = f2b(v); hb[q4*4+q] = h;
          float r = v - b2f(h);
          u16 mm_ = f2b(r); mb[q4*4+q] = mm_;
          if (NC == 3) lcb[q4*4+q] = f2b(r - b2f(mm_));
        }
      }
    }
    __syncthreads();
    if (GATHER){
      int base0 = (sseg*2)*1024 + sr*8;
      int base1 = (sseg*2+1)*1024 + sr*8;
      *(int4*)&lds[0*4096 + base0] = *(const int4*)&hb[0];
      *(int4*)&lds[0*4096 + base1] = *(const int4*)&hb[8];
      *(int4*)&lds[1*4096 + base0] = *(const int4*)&mb[0];
      *(int4*)&lds[1*4096 + base1] = *(const int4*)&mb[8];
      if (NC == 3){
        *(int4*)&lds[2*4096 + base0] = *(const int4*)&lcb[0];
        *(int4*)&lds[2*4096 + base1] = *(const int4*)&lcb[8];
      }
    } else {
#pragma unroll
      for (int cc=0; cc<NC; cc++){
        gl_lds16(Ap[cc] + gA0[cc] + k0, &lds[cc*4096 + lb0]);
        gl_lds16(Ap[cc] + gA1[cc] + k0, &lds[cc*4096 + lb1]);
      }
    }
#pragma unroll
    for (int cc=0; cc<NC; cc++){
      gl_lds16(Bp[cc] + gB0[cc] + k0, &lds[(NC+cc)*4096 + lb0]);
      gl_lds16(Bp[cc] + gB1[cc] + k0, &lds[(NC+cc)*4096 + lb1]);
    }
    __syncthreads();
    short8v fa[NC][4], fb[NC][4];
#pragma unroll
    for (int m=0;m<4;m++){
      int ra = l4*1024 + (wr + m*16 + l15)*8;
      int rb = l4*1024 + (wc + m*16 + l15)*8;
#pragma unroll
      for (int cc=0;cc<NC;cc++){
        fa[cc][m] = *(const short8v*)&lds[cc*4096 + ra];
        fb[cc][m] = *(const short8v*)&lds[(NC+cc)*4096 + rb];
      }
    }
#pragma unroll
    for (int m=0;m<4;m++)
#pragma unroll
      for (int n=0;n<4;n++){
        if (P == 3){
          acc[m][n] = __builtin_amdgcn_mfma_f32_16x16x32_bf16(fa[1][m], fb[1][n], acc[m][n], 0,0,0);
          acc[m][n] = __builtin_amdgcn_mfma_f32_16x16x32_bf16(fa[0][m], fb[2][n], acc[m][n], 0,0,0);
          acc[m][n] = __builtin_amdgcn_mfma_f32_16x16x32_bf16(fa[2][m], fb[0][n], acc[m][n], 0,0,0);
        }
        acc[m][n] = __builtin_amdgcn_mfma_f32_16x16x32_bf16(fa[0][m], fb[1][n], acc[m][n], 0,0,0);
        acc[m][n] = __builtin_amdgcn_mfma_f32_16x16x32_bf16(fa[1][m], fb[0][n], acc[m][n], 0,0,0);
        acc[m][n] = __builtin_amdgcn_mfma_f32_16x16x32_bf16(fa[0][m], fb[0][n], acc[m][n], 0,0,0);
      }
  }

  const float NEG = -__builtin_inff();
#pragma unroll
  for (int n=0;n<4;n++){
    int col0 = n0 + wc + n*16;
    if (col0 >= Nc) continue;
    int col = col0 + l15;
#pragma unroll
    for (int m=0;m<4;m++){
      int rowb = m0 + wr + m*16 + l4*4;
#pragma unroll
      for (int r=0;r<4;r++){
        int row = rowb + r;
        float v = acc[m][n][r];
        if ((flags & 2) && row == colbase + col) v = NEG;
        else v = (v >= 0.f) ? v : v*slope;
        if (col < Nc){
          if (flags & 1) v += Cf[(size_t)row*ldc + col];
          if (Cf) Cf[(size_t)row*ldc + col] = v;
          if (Ch){
            size_t o = (size_t)row*ldsp + cosp + col;
            u16 h = f2b(v); Ch[o] = h;
            float rr = v - b2f(h);
            u16 mm_ = f2b(rr); Cm[o] = mm_;
            if (Cl) Cl[(size_t)row*ldspl + col] = f2b(rr - b2f(mm_));
          }
        }
      }
    }
  }
}

// ---------------- kNN pieces ----------------
__global__ void k_normalize(const float* __restrict__ x,
                            u16* __restrict__ oh, u16* __restrict__ om,
                            u16* __restrict__ ol, int Dx){
  int i = blockIdx.x, lane = threadIdx.x;   // 64 lanes
  size_t o0 = (size_t)i*Dx + lane;
  float a = x[o0];
  float b = 0.f;
  if (Dx == 128) b = x[o0 + 64];
  float ss = a*a + b*b;
  for (int d = 32; d; d >>= 1) ss += __shfl_xor(ss, d);
  float rs = rsqrtf(ss + 1e-12f);
  float va = a*rs;
  u16 h = f2b(va); oh[o0] = h;
  float r = va - b2f(h);
  u16 mm_ = f2b(r); om[o0] = mm_;
  ol[o0] = f2b(r - b2f(mm_));
  if (Dx == 128){
    float vb = b*rs;
    u16 h2 = f2b(vb); oh[o0+64] = h2;
    float r2 = vb - b2f(h2);
    u16 m2 = f2b(r2); om[o0+64] = m2;
    ol[o0+64] = f2b(r2 - b2f(m2));
  }
}

// 4 rows/block (one row per wave). Running top-16 SORTED (value desc, idx asc)
// in lanes 0..15. SINGLE bounded path: exact 16-round selection over
// {running ∪ 1024 chunk candidates} — fixed cost, data-independent.
// tie-break: larger value, then smaller index (matches jax.lax.top_k).
__global__ void k_topk_merge(const float* __restrict__ S, int colbase,
                             float* __restrict__ topv, int* __restrict__ topi,
                             int first){
  const float INF = __builtin_inff();
  int i = blockIdx.x*4 + (threadIdx.x >> 6);
  int lane = threadIdx.x & 63;
  const float* row = S + (size_t)i * SCC;

  // hoisted coalesced loads (16B lane-stride)
  float4 va = *(const float4*)(row + 0*256 + lane*4);
  float4 vb = *(const float4*)(row + 1*256 + lane*4);
  float4 vc = *(const float4*)(row + 2*256 + lane*4);
  float4 vd = *(const float4*)(row + 3*256 + lane*4);
  float cv[16]; int cj[16];
  {
    float t0[4]={va.x,va.y,va.z,va.w}, t1[4]={vb.x,vb.y,vb.z,vb.w},
          t2[4]={vc.x,vc.y,vc.z,vc.w}, t3[4]={vd.x,vd.y,vd.z,vd.w};
#pragma unroll
    for (int q=0;q<4;q++){
      cv[q]    = t0[q]; cj[q]    = colbase + 0*256 + lane*4 + q;
      cv[4+q]  = t1[q]; cj[4+q]  = colbase + 1*256 + lane*4 + q;
      cv[8+q]  = t2[q]; cj[8+q]  = colbase + 2*256 + lane*4 + q;
      cv[12+q] = t3[q]; cj[12+q] = colbase + 3*256 + lane*4 + q;
    }
#pragma unroll
    for (int q=0;q<16;q++) if (cj[q] == i) cv[q] = -INF;
  }

  float pv = -INF; int pj = 0x7fffffff;
  if (!first && lane < 16){ pv = topv[i*16+lane]; pj = topi[i*16+lane]; }

  // exact 16-round selection over {running (lanes<16)} ∪ chunk candidates.
  float myv = -INF; int myj = 0x7fffffff;
#pragma unroll
  for (int r=0;r<16;r++){
    float lv = pv; int lj = pj;
#pragma unroll
    for (int q=0;q<16;q++){
      if ((cv[q] > lv) || (cv[q] == lv && cj[q] < lj)){ lv = cv[q]; lj = cj[q]; }
    }
    float bv = lv; int bj = lj;
    for (int d=32; d; d>>=1){
      float ov = __shfl_xor(bv, d); int oj = __shfl_xor(bj, d);
      if ((ov > bv) || (ov == bv && oj < bj)){ bv = ov; bj = oj; }
    }
    if (lj == bj){
      if (pj == bj) pv = -INF;
      else {
#pragma unroll
        for (int q=0;q<16;q++) if (cj[q] == bj) cv[q] = -INF;
      }
    }
    if (lane == r){ myv = bv; myj = bj; }
  }
  if (lane < 16){ topv[i*16+lane] = myv; topi[i*16+lane] = myj; }
}

// ---------------- dynamic layer pieces ----------------
__global__ void k_segmax_add(const float* __restrict__ mo, int H2, int c0,
                             float* __restrict__ outp){
  int ii = blockIdx.x;
  int c = threadIdx.x;
  float m = -INFINITY;
  for (int s=0;s<KEDGE;s++) m = fmaxf(m, mo[(size_t)(ii*KEDGE+s)*H2 + c]);
  outp[(size_t)(c0+ii)*H2 + c] += m;
}

// ---------------- BN ----------------
__global__ void k_bn_part(const float* __restrict__ X, int C,
                          float* __restrict__ psum, float* __restrict__ psq){
  int c = blockIdx.x*64 + (threadIdx.x & 63);
  int rl = threadIdx.x >> 6;
  int r0 = blockIdx.y * 512;
  float s = 0.f, q = 0.f;
  for (int r = r0 + rl; r < r0 + 512; r += 4){
    float v = X[(size_t)r*C + c];
    s += v; q += v*v;
  }
  __shared__ float ls[256], lq[256];
  ls[threadIdx.x] = s; lq[threadIdx.x] = q;
  __syncthreads();
  if (rl == 0){
    int tt = threadIdx.x;
    psum[blockIdx.y*C + c] = ls[tt] + ls[tt+64] + ls[tt+128] + ls[tt+192];
    psq [blockIdx.y*C + c] = lq[tt] + lq[tt+64] + lq[tt+128] + lq[tt+192];
  }
}
__global__ void k_bn_stats(const float* __restrict__ psum, const float* __restrict__ psq,
                           int C, float* __restrict__ stat){
  int c = blockIdx.x*256 + threadIdx.x; if (c >= C) return;
  float s = 0.f, q = 0.f;
  for (int ch=0; ch<32; ch++){ s += psum[ch*C + c]; q += psq[ch*C + c]; }
  float m = s * (1.f/16384.f);
  float var = q * (1.f/16384.f) - m*m;
  stat[c] = m;
  stat[C + c] = rsqrtf(var + 1e-5f);
}
// writes lrelu(bn(x),0.2) as h/m into Oh/Om at [row*ldo + co + c]
__global__ void k_bn_apply(const float* __restrict__ X, int Cshift, int C,
                           const float* __restrict__ stat,
                           const float* __restrict__ g, const float* __restrict__ b,
                           u16* __restrict__ Oh, u16* __restrict__ Om,
                           int ldo, int co, int total){
  for (int idx = blockIdx.x*256 + threadIdx.x; idx < total; idx += gridDim.x*256){
    int c = idx & (C-1);
    int r = idx >> Cshift;
    float v = (X[idx] - stat[c]) * stat[C + c] * g[c] + b[c];
    v = (v >= 0.f) ? v : 0.2f*v;
    size_t o = (size_t)r*ldo + co + c;
    u16 h = f2b(v); Oh[o] = h;
    Om[o] = f2b(v - b2f(h));
  }
}

// ---------------- host ----------------
extern "C" void kernel_launch(void* const* d_in, const int* in_sizes, int n_in,
                              void* d_out, int out_size, void* d_ws, size_t ws_size,
                              hipStream_t stream) {
  (void)in_sizes; (void)n_in; (void)out_size; (void)ws_size;
  const float* x0   = (const float*)d_in[0];
  const float* ea   = (const float*)d_in[1];
  const int*   ei   = (const int*)d_in[2];
  const float* f1_g = (const float*)d_in[23];
  const float* f1_b = (const float*)d_in[24];
  const float* f2_g1= (const float*)d_in[26];
  const float* f2_b1= (const float*)d_in[27];
  const float* f2_g2= (const float*)d_in[29];
  const float* f2_b2= (const float*)d_in[30];
  float* out = (float*)d_out;

  const float* wsrc[22] = {
    (const float*)d_in[4],(const float*)d_in[5],(const float*)d_in[6],(const float*)d_in[7],
    (const float*)d_in[8],(const float*)d_in[9],(const float*)d_in[10],(const float*)d_in[11],
    (const float*)d_in[12],(const float*)d_in[13],(const float*)d_in[14],(const float*)d_in[15],
    (const float*)d_in[16],(const float*)d_in[17],(const float*)d_in[18],
    (const float*)d_in[19],(const float*)d_in[20],(const float*)d_in[21],
    (const float*)d_in[22],(const float*)d_in[25],(const float*)d_in[28],(const float*)d_in[31]
  };
  const int wK[22] = {128,96,64,64, 128,128,128,64, 192,192,192,128,
                      128,128,64, 256,192,128, 704, 1728, 512, 256};
  const int wN[22] = {96,64,64,64, 128,128,128,128, 192,192,192,192,
                      128,128,128, 192,192,192, 1024, 512, 256, 128};
  int wNp[22];
  for (int i=0;i<22;i++) wNp[i] = (wN[i] + 127) & ~127;

  char* w = (char*)d_ws;
  size_t off = 0;
  auto alloc = [&](size_t bytes)->char*{
    char* p = w + off; off = (off + bytes + 255) & ~(size_t)255; return p;
  };
  // fp32 persistents
  float* sg1f = (float*)alloc((size_t)NN*64*4);
  float* sg2f = (float*)alloc((size_t)NN*128*4);
  float* dg1f = (float*)alloc((size_t)NN*128*4);
  // cat1 split store: cols [sg1 0:64 | dg1 64:192 | dg2 192:384 | sg2 384:512 | sg3 512:704]
  u16* cat1h = (u16*)alloc((size_t)NN*704*2);
  u16* cat1m = (u16*)alloc((size_t)NN*704*2);
  u16* sg1l  = (u16*)alloc((size_t)NN*64*2);
  u16* dg1l  = (u16*)alloc((size_t)NN*128*2);
  float* bnp  = (float*)alloc((size_t)2*32*1024*4);
  float* bns  = (float*)alloc((size_t)2*1024*4);
  u16 *wh[22], *wm[22], *wl[22];
  for (int i=0;i<22;i++){
    size_t e = (size_t)wK[i]*wNp[i];
    wh[i] = (u16*)alloc(e*2); wm[i] = (u16*)alloc(e*2); wl[i] = (u16*)alloc(e*2);
  }
  char* arena = alloc((size_t)120*1024*1024);
  size_t ac = 0;
  auto aalloc = [&](size_t b)->char*{
    char* p = arena + ac; ac = (ac + b + 255) & ~(size_t)255; return p;
  };

  auto MG = [&](int P, const u16* Ah, const u16* Am, const u16* Al, int lda, int ldal,
                const u16* Bh, const u16* Bm, const u16* Bl, int ldb,
                float* Cf, u16* Ch, u16* Cm, u16* Cl, int ldc, int ldsp, int cosp, int ldspl,
                int M, int K, int Nc, float slope, int flags, int colbase){
    dim3 g((Nc+127)/128, M/128);
    if (P == 3)
      k_mgemm<3,0><<<g,256,0,stream>>>(Ah,Am,Al,lda,ldal,Bh,Bm,Bl,ldb,
        Cf,Ch,Cm,Cl,ldc,ldsp,cosp,ldspl,K,Nc,slope,flags,colbase,nullptr,nullptr,0,0);
    else
      k_mgemm<2,0><<<g,256,0,stream>>>(Ah,Am,Al,lda,ldal,Bh,Bm,Bl,ldb,
        Cf,Ch,Cm,Cl,ldc,ldsp,cosp,ldspl,K,Nc,slope,flags,colbase,nullptr,nullptr,0,0);
  };
  auto MGG = [&](int P, const float* Xf, const int* topig, int c0g, int Dxg,
                 const u16* Bh, const u16* Bm, const u16* Bl, int ldb,
                 u16* Ch, u16* Cm, u16* Cl, int ldsp, int ldspl,
                 int M, int Nc, float slope){
    dim3 g((Nc+127)/128, M/128);
    if (P == 3)
      k_mgemm<3,1><<<g,256,0,stream>>>(nullptr,nullptr,nullptr,0,0,Bh,Bm,Bl,ldb,
        nullptr,Ch,Cm,Cl,0,ldsp,0,ldspl,2*Dxg,Nc,slope,0,0,Xf,topig,c0g,Dxg);
    else
      k_mgemm<2,1><<<g,256,0,stream>>>(nullptr,nullptr,nullptr,0,0,Bh,Bm,Bl,ldb,
        nullptr,Ch,Cm,Cl,0,ldsp,0,ldspl,2*Dxg,Nc,slope,0,0,Xf,topig,c0g,Dxg);
  };

  // -------- weight prep (padded) --------
  for (int i=0;i<22;i++){
    int e = wK[i]*wNp[i];
    k_wprep3<<<(e+255)/256, 256, 0, stream>>>(wsrc[i], wK[i], wN[i], wNp[i], wh[i], wm[i], wl[i]);
  }

  // -------- static-phase arena --------
  ac = 0;
  u16* t1s[3]; for (int c=0;c<3;c++) t1s[c] = (u16*)aalloc((size_t)NN*192*2);
  u16* t2s[3]; for (int c=0;c<3;c++) t2s[c] = (u16*)aalloc((size_t)NN*192*2);
  float* sof32 = (float*)aalloc((size_t)NN*192*4);
  int* csr_cnt = (int*)aalloc((size_t)NN*4);
  int* csr_off = (int*)aalloc((size_t)(NN+1)*4);
  int* csr_src = (int*)aalloc((size_t)NE*4);
  int* csr_eid = (int*)aalloc((size_t)NE*4);
  u16* x0s[3]; for (int c=0;c<3;c++) x0s[c] = (u16*)aalloc((size_t)NN*64*2);

  k_split3<<<(NN*64+255)/256, 256, 0, stream>>>(x0, x0s[0], x0s[1], x0s[2], NN*64, 64, 64, 0, 64);

  // -------- CSR build --------
  const int* srcp = ei;
  const int* dstp = ei + NE;
  k_fill_i32<<<(NN+255)/256, 256, 0, stream>>>(csr_cnt, 0, NN);
  k_hist<<<NE/256, 256, 0, stream>>>(dstp, csr_cnt);
  k_scan<<<1, 1024, 0, stream>>>(csr_cnt, csr_off);
  k_fill_i32<<<(NN+255)/256, 256, 0, stream>>>(csr_cnt, 0, NN);
  k_csr_fill<<<NE/256, 256, 0, stream>>>(srcp, dstp, csr_off, csr_cnt, csr_src, csr_eid);

  // -------- static layers --------
  auto static_layer = [&](int P, const float* xf,
                          const u16* xh, const u16* xm, const u16* xl, int lda, int ldal,
                          int Dx, int wi, float* of, int co, u16* lout, int H1, int H2){
    int DM = Dx + 64;
    k_static_segmax<<<NN, DM, 0, stream>>>(xf, Dx, ea, csr_off, csr_src, csr_eid,
                                           t1s[0], t1s[1], t1s[2]);
    MG(P, t1s[0],t1s[1],t1s[2], DM,DM, wh[wi],wm[wi],wl[wi], DM,
       nullptr, t2s[0],t2s[1],t2s[2], 0, H1,0,H1, NN, DM, H1, 0.1f, 0, 0);
    MG(P, t2s[0],t2s[1],t2s[2], H1,H1, wh[wi+1],wm[wi+1],wl[wi+1], H1,
       nullptr, t1s[0],t1s[1],t1s[2], 0, H2,0,H2, NN, H1, H2, 0.1f, 0, 0);
    MG(P, xh,xm,xl, lda,ldal, wh[wi+3],wm[wi+3],wl[wi+3], Dx,
       of, nullptr,nullptr,nullptr, H2,0,0,0, NN, Dx, H2, 0.1f, 0, 0);          // of = lrelu(x@lin)
    MG(P, t1s[0],t1s[1],t1s[2], H2,H2, wh[wi+2],wm[wi+2],wl[wi+2], H2,
       of, cat1h,cat1m,lout, H2, 704,co,(lout? (co==0?64:128) : 0),
       NN, H2, H2, 0.1f, 1, 0);                                                  // of += lrelu(h@w3)
  };
  static_layer(3, x0,  x0s[0],x0s[1],x0s[2], 64,64, 64, 0, sg1f, 0,   sg1l, 96, 64);
  static_layer(2, sg1f, cat1h+0,  cat1m+0,  nullptr, 704,0, 64, 4, sg2f, 384, nullptr, 128, 128);
  static_layer(2, sg2f, cat1h+384,cat1m+384,nullptr, 704,0, 128,8, sof32,512, nullptr, 192, 192);

  // -------- dynamic-phase arena --------
  ac = 0;
  u16* xns[3]; for (int c=0;c<3;c++) xns[c] = (u16*)aalloc((size_t)NN*128*2);
  float* topv = (float*)aalloc((size_t)NN*16*4);
  int*   topi = (int*)aalloc((size_t)NN*16*4);
  float* dg2of = (float*)aalloc((size_t)NN*192*4);
  size_t dyn0 = ac;

  auto dyn_layer = [&](int P, const float* xf,
                       const u16* xh, const u16* xm, const u16* xl, int lda, int ldal,
                       int Dx, int wi, float* ofp, int co, u16* lout, int H1, int H2, int nch){
    const int R = nch*KEDGE;   // mult of 128
    ac = dyn0;
    float* S = (float*)aalloc((size_t)NN*SCC*4);
    ac = dyn0;   // alias: S dead once topk loop finishes
    u16* mms[3]; for (int c=0;c<3;c++) mms[c] = (u16*)aalloc((size_t)R*H1*2);
    float* mout = (float*)aalloc((size_t)R*H2*4);

    k_normalize<<<NN, 64, 0, stream>>>(xf, xns[0], xns[1], xns[2], Dx);
    for (int cb = 0; cb < NN; cb += SCC){
      MG(3, xns[0],xns[1],xns[2], Dx,Dx,
         xns[0]+(size_t)cb*Dx, xns[1]+(size_t)cb*Dx, xns[2]+(size_t)cb*Dx, Dx,
         S, nullptr,nullptr,nullptr, SCC,0,0,0, NN, Dx, SCC, 1.0f, 2, cb);
      k_topk_merge<<<NN/4, 256, 0, stream>>>(S, cb, topv, topi, cb == 0);
    }
    MG(P, xh,xm,xl, lda,ldal, wh[wi+2],wm[wi+2],wl[wi+2], Dx,
       ofp, nullptr,nullptr,nullptr, H2,0,0,0, NN, Dx, H2, 0.1f, 0, 0);   // ofp = lrelu(x@lin)
    for (int c0 = 0; c0 < NN; c0 += nch){
      MGG(P, xf, topi, c0, Dx, wh[wi],wm[wi],wl[wi], 2*Dx,
          mms[0],mms[1],(P==3?mms[2]:nullptr), H1,H1, R, H1, 0.2f);
      MG(P, mms[0],mms[1],mms[2], H1,H1, wh[wi+1],wm[wi+1],wl[wi+1], H1,
         mout, nullptr,nullptr,nullptr, H2,0,0,0, R, H1, H2, 0.2f, 0, 0);
      k_segmax_add<<<nch, H2, 0, stream>>>(mout, H2, c0, ofp);            // ofp += segmax
    }
    k_split3<<<(NN*H2+255)/256, 256, 0, stream>>>(ofp, cat1h, cat1m, lout,
                                                  NN*H2, H2, 704, co, H2);
  };
  dyn_layer(3, sg1f, cat1h+0, cat1m+0, sg1l, 704,64, 64,  12, dg1f, 64,  dg1l, 128, 128, 4096);
  dyn_layer(2, dg1f, cat1h+64,cat1m+64,nullptr,704,0, 128, 15, dg2of,192, nullptr,192, 192, 2048);

  // -------- fusion-phase arena --------
  ac = 0;
  u16*   f1sh = (u16*)aalloc((size_t)NN*1024*2);   // f1 splits [NN,1024]
  u16*   f1sm = (u16*)aalloc((size_t)NN*1024*2);
  float* fscr = (float*)aalloc((size_t)NN*512*4);  // fp32 scratch [NN,512]
  // aliases once producers are dead:
  u16* h2h = f1sh;
  u16* h2m = f1sm;
  float* h3f32 = (float*)(f1sm + (size_t)NN*512);
  u16* h3h = f1sh + (size_t)NN*512;
  u16* h3m = h3h + (size_t)NN*256;

  auto bn = [&](const float* X, int C, int Cshift, const float* g, const float* b,
                u16* Oh, u16* Om, int ldo, int co){
    k_bn_part<<<dim3(C/64, 32), 256, 0, stream>>>(X, C, bnp, bnp + 32*1024);
    k_bn_stats<<<(C+255)/256, 256, 0, stream>>>(bnp, bnp + 32*1024, C, bns);
    k_bn_apply<<<2048, 256, 0, stream>>>(X, Cshift, C, bns, g, b, Oh, Om, ldo, co, NN*C);
  };

  // f1 in two 512-col halves: fscr = cat1 @ f1_w[:, p*512:...] ; bn -> f1s
  for (int p = 0; p < 2; p++){
    MG(2, cat1h,cat1m,nullptr, 704,0, wh[18]+(size_t)p*512*704, wm[18]+(size_t)p*512*704, nullptr, 704,
       fscr, nullptr,nullptr,nullptr, 512,0,0,0, NN, 704, 512, 1.f, 0, 0);
    bn(fscr, 512, 9, f1_g + p*512, f1_b + p*512, f1sh, f1sm, 1024, p*512);
  }
  // h2 = lrelu(bn(cat2 @ f2_w1)) ; cat2 = [f1 | cat1]
  MG(2, f1sh,f1sm,nullptr, 1024,0, wh[19],wm[19],nullptr, 1728,
     fscr, nullptr,nullptr,nullptr, 512,0,0,0, NN, 1024, 512, 1.f, 0, 0);
  MG(2, cat1h,cat1m,nullptr, 704,0, wh[19]+1024,wm[19]+1024,nullptr, 1728,
     fscr, nullptr,nullptr,nullptr, 512,0,0,0, NN, 704, 512, 1.f, 1, 0);
  bn(fscr, 512, 9, f2_g1, f2_b1, h2h, h2m, 512, 0);
  MG(2, h2h,h2m,nullptr, 512,0, wh[20],wm[20],nullptr, 512,
     h3f32, nullptr,nullptr,nullptr, 256,0,0,0, NN, 512, 256, 1.f, 0, 0);
  bn(h3f32, 256, 8, f2_g2, f2_b2, h3h, h3m, 256, 0);
  MG(2, h3h,h3m,nullptr, 256,0, wh[21],wm[21],nullptr, 256,
     out, nullptr,nullptr,nullptr, 128,0,0,0, NN, 256, 128, 1.f, 0, 0);
}

// Round 15
// 4294.135 us; speedup vs baseline: 1.4924x; 1.4924x over previous
//
#include <hip/hip_runtime.h>
#include <math.h>

typedef unsigned short u16;
typedef unsigned int u32;
typedef unsigned long long u64;
typedef __attribute__((ext_vector_type(8))) short short8v;
typedef __attribute__((ext_vector_type(4))) float f32x4;

static const int NN  = 16384;
static const int NE  = 524288;
static const int SCC = 1024;   // sim column chunk
static const int KEDGE = 17;

__device__ __forceinline__ u16 f2b(float v){
  u32 u = __float_as_uint(v);
  u += 0x7FFFu + ((u >> 16) & 1u);
  return (u16)(u >> 16);
}
__device__ __forceinline__ float b2f(u16 h){ return __uint_as_float(((u32)h) << 16); }

// async 16B global->LDS (gfx950). LDS dest is wave-uniform base + lane*16.
__device__ __forceinline__ void gl_lds16(const u16* g, u16* l){
  __builtin_amdgcn_global_load_lds(
      (const __attribute__((address_space(1))) u32*)(g),
      (__attribute__((address_space(3))) u32*)(l), 16, 0, 0);
}

// ---------------- utility ----------------
__global__ void k_fill_i32(int* p, int v, int n){
  int i = blockIdx.x*256 + threadIdx.x; if (i < n) p[i] = v;
}
// fp32 [n] (rows of C) -> h/m at [r*ldo+co+c], l (optional) at [r*ldl+c]
__global__ void k_split3(const float* __restrict__ s, u16* __restrict__ h,
                         u16* __restrict__ m, u16* __restrict__ l, int n,
                         int C, int ldo, int co, int ldl){
  int i = blockIdx.x*256 + threadIdx.x; if (i >= n) return;
  int r = i / C, c = i % C;
  float v = s[i];
  u16 hh = f2b(v);
  float rr = v - b2f(hh);
  u16 mm_ = f2b(rr);
  size_t o = (size_t)r*ldo + co + c;
  h[o] = hh; m[o] = mm_;
  if (l) l[(size_t)r*ldl + c] = f2b(rr - b2f(mm_));
}
// W [K,N] fp32 -> Wt [Npad,K] 3-way split, zero rows for n >= N
__global__ void k_wprep3(const float* __restrict__ W, int K, int N, int Npad,
                         u16* __restrict__ h, u16* __restrict__ m, u16* __restrict__ l){
  int idx = blockIdx.x*256 + threadIdx.x; if (idx >= K*Npad) return;
  int n = idx / K, k = idx % K;
  float v = (n < N) ? W[(size_t)k*N + n] : 0.f;
  u16 hh = f2b(v); h[idx] = hh;
  float r = v - b2f(hh);
  u16 mm_ = f2b(r); m[idx] = mm_;
  l[idx] = f2b(r - b2f(mm_));
}

// ---------------- CSR build ----------------
__global__ void k_hist(const int* __restrict__ dst, int* __restrict__ cnt){
  int e = blockIdx.x*256 + threadIdx.x; if (e < NE) atomicAdd(&cnt[dst[e]], 1);
}
__global__ void k_scan(const int* __restrict__ cnt, int* __restrict__ off){
  __shared__ int part[1024];
  int t = threadIdx.x;
  int base = t*16;
  int loc[16]; int s = 0;
#pragma unroll
  for (int q=0;q<16;q++){ loc[q] = s; s += cnt[base+q]; }
  part[t] = s; __syncthreads();
  for (int d=1; d<1024; d<<=1){
    int v = (t>=d) ? part[t-d] : 0; __syncthreads();
    part[t] += v; __syncthreads();
  }
  int prev = (t==0) ? 0 : part[t-1];
#pragma unroll
  for (int q=0;q<16;q++) off[base+q] = prev + loc[q];
  if (t == 1023) off[NN] = part[1023];
}
__global__ void k_csr_fill(const int* __restrict__ src, const int* __restrict__ dst,
                           const int* __restrict__ off, int* __restrict__ cur,
                           int* __restrict__ csrc, int* __restrict__ ceid){
  int e = blockIdx.x*256 + threadIdx.x; if (e >= NE) return;
  int d = dst[e];
  int p = atomicAdd(&cur[d], 1);
  int idx = off[d] + p;
  csrc[idx] = src[e];
  ceid[idx] = e;
}

// ---------------- static segment-max (fp32 in, split3 out) ----------------
__global__ void k_static_segmax(const float* __restrict__ x, int Dx,
                                const float* __restrict__ ea,
                                const int* __restrict__ off,
                                const int* __restrict__ csrc,
                                const int* __restrict__ ceid,
                                u16* __restrict__ th, u16* __restrict__ tm,
                                u16* __restrict__ tl){
  int i = blockIdx.x, c = threadIdx.x;
  int DM = Dx + 64;
  int s = off[i], e = off[i+1];
  float mx = -INFINITY;
  float v;
  if (c < Dx){
    for (int t = s; t < e; t++) mx = fmaxf(mx, x[(size_t)csrc[t]*Dx + c]);
    v = (s == e) ? 0.f : (mx - x[(size_t)i*Dx + c]);
  } else {
    int cc = c - Dx;
    for (int t = s; t < e; t++) mx = fmaxf(mx, ea[(size_t)ceid[t]*64 + cc]);
    v = (s == e) ? 0.f : mx;
  }
  size_t o = (size_t)i*DM + c;
  u16 h = f2b(v); th[o] = h;
  float r = v - b2f(h);
  u16 mm_ = f2b(r); tm[o] = mm_;
  tl[o] = f2b(r - b2f(mm_));
}

// ---------------- MFMA GEMM over 3-way splits (global_load_lds staging) -------
// (round-7 form; no swizzle, no Smax epilogue)
template<int P, int GATHER>
__global__ __launch_bounds__(256) void k_mgemm(
    const u16* __restrict__ Ah, const u16* __restrict__ Am, const u16* __restrict__ Al,
    int lda, int ldal,
    const u16* __restrict__ Bh, const u16* __restrict__ Bm, const u16* __restrict__ Bl,
    int ldb,
    float* __restrict__ Cf, u16* __restrict__ Ch, u16* __restrict__ Cm, u16* __restrict__ Cl,
    int ldc, int ldsp, int cosp, int ldspl,
    int K, int Nc, float slope, int flags, int colbase,
    const float* __restrict__ Xf, const int* __restrict__ topig, int c0g, int Dxg)
{
  constexpr int NC = (P == 3) ? 3 : 2;
  __shared__ u16 lds[NC*2*4096];
  const int t = threadIdx.x;
  const int m0 = blockIdx.y * 128, n0 = blockIdx.x * 128;
  const int wave = t >> 6, lane = t & 63;
  const int wr = (wave >> 1) << 6, wc = (wave & 1) << 6;
  const int l15 = lane & 15, l4 = lane >> 4;
  f32x4 acc[4][4] = {};

  const u16* Ap[3] = {Ah, Am, Al};
  const int ldav[3] = {lda, lda, ldal};
  const u16* Bp[3] = {Bh, Bm, Bl};

  const int c0c = wave*128 + lane, c1c = c0c + 64;
  const int r0c = c0c & 127, s0c = c0c >> 7;
  const int r1c = c1c & 127, s1c = c1c >> 7;
  const int lb0 = (wave*128)*8;
  const int lb1 = (wave*128 + 64)*8;

  size_t gA0[3], gA1[3], gB0[3], gB1[3];
#pragma unroll
  for (int cc=0; cc<NC; cc++){
    if (!GATHER){
      gA0[cc] = (size_t)(m0 + r0c)*ldav[cc] + s0c*8;
      gA1[cc] = (size_t)(m0 + r1c)*ldav[cc] + s1c*8;
    }
    gB0[cc] = (size_t)(n0 + r0c)*ldb + s0c*8;
    gB1[cc] = (size_t)(n0 + r1c)*ldb + s1c*8;
  }

  const int sr = t & 127, sseg = t >> 7;
  int node_i = 0, node_j = 0;
  if (GATHER){
    int erow = m0 + sr;
    int i = c0g + erow / KEDGE;
    int slot = erow % KEDGE;
    node_i = i;
    node_j = (slot < 16) ? topig[i*16 + slot] : i;
  }

  for (int k0 = 0; k0 < K; k0 += 32){
    __attribute__((aligned(16))) u16 hb[16], mb[16], lcb[16];
    if (GATHER){
      int kpos = k0 + sseg*16;
      bool side = kpos < Dxg;
      int kk = side ? kpos : kpos - Dxg;
      const float* xi = Xf + (size_t)node_i*Dxg + kk;
      const float* xj = Xf + (size_t)node_j*Dxg + kk;
#pragma unroll
      for (int q4=0;q4<4;q4++){
        float4 a = *(const float4*)(xi + q4*4);
        if (!side){
          float4 b = *(const float4*)(xj + q4*4);
          a = make_float4(b.x-a.x, b.y-a.y, b.z-a.z, b.w-a.w);
        }
        float vv[4] = {a.x, a.y, a.z, a.w};
#pragma unroll
        for (int q=0;q<4;q++){
          float v = vv[q];
          u16 h = f2b(v); hb[q4*4+q] = h;
          float r = v - b2f(h);
          u16 mm_ = f2b(r); mb[q4*4+q] = mm_;
          if (NC == 3) lcb[q4*4+q] = f2b(r - b2f(mm_));
        }
      }
    }
    __syncthreads();
    if (GATHER){
      int base0 = (sseg*2)*1024 + sr*8;
      int base1 = (sseg*2+1)*1024 + sr*8;
      *(int4*)&lds[0*4096 + base0] = *(const int4*)&hb[0];
      *(int4*)&lds[0*4096 + base1] = *(const int4*)&hb[8];
      *(int4*)&lds[1*4096 + base0] = *(const int4*)&mb[0];
      *(int4*)&lds[1*4096 + base1] = *(const int4*)&mb[8];
      if (NC == 3){
        *(int4*)&lds[2*4096 + base0] = *(const int4*)&lcb[0];
        *(int4*)&lds[2*4096 + base1] = *(const int4*)&lcb[8];
      }
    } else {
#pragma unroll
      for (int cc=0; cc<NC; cc++){
        gl_lds16(Ap[cc] + gA0[cc] + k0, &lds[cc*4096 + lb0]);
        gl_lds16(Ap[cc] + gA1[cc] + k0, &lds[cc*4096 + lb1]);
      }
    }
#pragma unroll
    for (int cc=0; cc<NC; cc++){
      gl_lds16(Bp[cc] + gB0[cc] + k0, &lds[(NC+cc)*4096 + lb0]);
      gl_lds16(Bp[cc] + gB1[cc] + k0, &lds[(NC+cc)*4096 + lb1]);
    }
    __syncthreads();
    short8v fa[NC][4], fb[NC][4];
#pragma unroll
    for (int m=0;m<4;m++){
      int ra = l4*1024 + (wr + m*16 + l15)*8;
      int rb = l4*1024 + (wc + m*16 + l15)*8;
#pragma unroll
      for (int cc=0;cc<NC;cc++){
        fa[cc][m] = *(const short8v*)&lds[cc*4096 + ra];
        fb[cc][m] = *(const short8v*)&lds[(NC+cc)*4096 + rb];
      }
    }
#pragma unroll
    for (int m=0;m<4;m++)
#pragma unroll
      for (int n=0;n<4;n++){
        if (P == 3){
          acc[m][n] = __builtin_amdgcn_mfma_f32_16x16x32_bf16(fa[1][m], fb[1][n], acc[m][n], 0,0,0);
          acc[m][n] = __builtin_amdgcn_mfma_f32_16x16x32_bf16(fa[0][m], fb[2][n], acc[m][n], 0,0,0);
          acc[m][n] = __builtin_amdgcn_mfma_f32_16x16x32_bf16(fa[2][m], fb[0][n], acc[m][n], 0,0,0);
        }
        acc[m][n] = __builtin_amdgcn_mfma_f32_16x16x32_bf16(fa[0][m], fb[1][n], acc[m][n], 0,0,0);
        acc[m][n] = __builtin_amdgcn_mfma_f32_16x16x32_bf16(fa[1][m], fb[0][n], acc[m][n], 0,0,0);
        acc[m][n] = __builtin_amdgcn_mfma_f32_16x16x32_bf16(fa[0][m], fb[0][n], acc[m][n], 0,0,0);
      }
  }

  const float NEG = -__builtin_inff();
#pragma unroll
  for (int n=0;n<4;n++){
    int col0 = n0 + wc + n*16;
    if (col0 >= Nc) continue;
    int col = col0 + l15;
#pragma unroll
    for (int m=0;m<4;m++){
      int rowb = m0 + wr + m*16 + l4*4;
#pragma unroll
      for (int r=0;r<4;r++){
        int row = rowb + r;
        float v = acc[m][n][r];
        if ((flags & 2) && row == colbase + col) v = NEG;
        else v = (v >= 0.f) ? v : v*slope;
        if (col < Nc){
          if (flags & 1) v += Cf[(size_t)row*ldc + col];
          if (Cf) Cf[(size_t)row*ldc + col] = v;
          if (Ch){
            size_t o = (size_t)row*ldsp + cosp + col;
            u16 h = f2b(v); Ch[o] = h;
            float rr = v - b2f(h);
            u16 mm_ = f2b(rr); Cm[o] = mm_;
            if (Cl) Cl[(size_t)row*ldspl + col] = f2b(rr - b2f(mm_));
          }
        }
      }
    }
  }
}

// ---------------- kNN pieces ----------------
__global__ void k_normalize(const float* __restrict__ x,
                            u16* __restrict__ oh, u16* __restrict__ om,
                            u16* __restrict__ ol, int Dx){
  int i = blockIdx.x, lane = threadIdx.x;   // 64 lanes
  size_t o0 = (size_t)i*Dx + lane;
  float a = x[o0];
  float b = 0.f;
  if (Dx == 128) b = x[o0 + 64];
  float ss = a*a + b*b;
  for (int d = 32; d; d >>= 1) ss += __shfl_xor(ss, d);
  float rs = rsqrtf(ss + 1e-12f);
  float va = a*rs;
  u16 h = f2b(va); oh[o0] = h;
  float r = va - b2f(h);
  u16 mm_ = f2b(r); om[o0] = mm_;
  ol[o0] = f2b(r - b2f(mm_));
  if (Dx == 128){
    float vb = b*rs;
    u16 h2 = f2b(vb); oh[o0+64] = h2;
    float r2 = vb - b2f(h2);
    u16 m2 = f2b(r2); om[o0+64] = m2;
    ol[o0+64] = f2b(r2 - b2f(m2));
  }
}

// 4 rows per block (4 waves). Running top-16 SORTED (value desc, index asc)
// in lanes 0..15. COALESCED loads: round r covers cols [r*256,(r+1)*256),
// lane reads float4 at r*256+lane*4 (16B lane-stride). Common path: one
// ballot per round; inserts only when a round has survivors (exact re-check
// per survivor vs the live threshold). First chunk: exact 16-round selection.
// tie-break everywhere: larger value, then smaller index (matches jax.lax.top_k)
__global__ void k_topk_merge(const float* __restrict__ S, int colbase,
                             float* __restrict__ topv, int* __restrict__ topi,
                             int first){
  const float INF = __builtin_inff();
  int i = blockIdx.x*4 + (threadIdx.x >> 6);
  int lane = threadIdx.x & 63;
  const float* row = S + (size_t)i * SCC;

  if (!first){
    float pv = -INF; int pj = 0x7fffffff;
    if (lane < 16){ pv = topv[i*16+lane]; pj = topi[i*16+lane]; }
    float tv = __shfl(pv, 15); int tj = __shfl(pj, 15);   // current worst
    bool dirty = false;
#pragma unroll
    for (int r4=0; r4<4; r4++){
      int cb = r4*256 + lane*4;
      float4 v4 = *(const float4*)(row + cb);
      float vv[4] = {v4.x, v4.y, v4.z, v4.w};
      int js[4]; bool sv[4]; bool any = false;
#pragma unroll
      for (int q=0;q<4;q++){
        int j = colbase + cb + q;
        float v = vv[q];
        if (j == i) v = -INF;
        vv[q] = v; js[q] = j;
        sv[q] = (v > tv) || (v == tv && j < tj);
        any |= sv[q];
      }
      if (__ballot(any) == 0) continue;
#pragma unroll
      for (int q=0;q<4;q++){
        u64 msk = __ballot(sv[q]);
        while (msk){
          int src = __ffsll((long long)msk) - 1; msk &= msk - 1;
          float v = __shfl(vv[q], src);
          int   j = __shfl(js[q], src);
          if ((v > tv) || (v == tv && j < tj)){        // re-check vs live thr
            bool eb = (pv > v) || (pv == v && pj < j);
            u32 mb = (u32)__ballot(eb) & 0xFFFFu;
            int p = __popc(mb);
            float svv = __shfl_up(pv, 1); int sjj = __shfl_up(pj, 1);
            if (lane < 16 && lane >= p){
              if (lane == p){ pv = v; pj = j; }
              else          { pv = svv; pj = sjj; }
            }
            tv = __shfl(pv, 15); tj = __shfl(pj, 15);
            dirty = true;
          }
        }
      }
    }
    if (dirty && lane < 16){ topv[i*16+lane] = pv; topi[i*16+lane] = pj; }
    return;
  }

  // first chunk: exact 16-round selection (lane r gets r-th best -> sorted)
  float cv[16]; int cj[16];
#pragma unroll
  for (int r4=0;r4<4;r4++){
    int cb = r4*256 + lane*4;
    float4 v4 = *(const float4*)(row + cb);
    float vv[4] = {v4.x, v4.y, v4.z, v4.w};
#pragma unroll
    for (int q=0;q<4;q++){
      int j = colbase + cb + q;
      float v = vv[q];
      if (j == i) v = -INF;
      cv[r4*4+q] = v; cj[r4*4+q] = j;
    }
  }
  float myv = -INF; int myj = 0;
#pragma unroll
  for (int r=0;r<16;r++){
    float lv = -INF; int lj = 0x7fffffff;
#pragma unroll
    for (int q=0;q<16;q++){
      bool better = (cv[q] > lv) || (cv[q] == lv && cj[q] < lj);
      if (better){ lv = cv[q]; lj = cj[q]; }
    }
    float bv = lv; int bj = lj;
    for (int d=32; d; d>>=1){
      float ov = __shfl_xor(bv, d);
      int oj = __shfl_xor(bj, d);
      bool better = (ov > bv) || (ov == bv && oj < bj);
      if (better){ bv = ov; bj = oj; }
    }
#pragma unroll
    for (int q=0;q<16;q++) if (cj[q] == bj) cv[q] = -INF;
    if (lane == r){ myv = bv; myj = bj; }
  }
  if (lane < 16){ topv[i*16+lane] = myv; topi[i*16+lane] = myj; }
}

// ---------------- dynamic layer pieces ----------------
__global__ void k_segmax_add(const float* __restrict__ mo, int H2, int c0,
                             float* __restrict__ outp){
  int ii = blockIdx.x;
  int c = threadIdx.x;
  float m = -INFINITY;
  for (int s=0;s<KEDGE;s++) m = fmaxf(m, mo[(size_t)(ii*KEDGE+s)*H2 + c]);
  outp[(size_t)(c0+ii)*H2 + c] += m;
}

// ---------------- BN ----------------
__global__ void k_bn_part(const float* __restrict__ X, int C,
                          float* __restrict__ psum, float* __restrict__ psq){
  int c = blockIdx.x*64 + (threadIdx.x & 63);
  int rl = threadIdx.x >> 6;
  int r0 = blockIdx.y * 512;
  float s = 0.f, q = 0.f;
  for (int r = r0 + rl; r < r0 + 512; r += 4){
    float v = X[(size_t)r*C + c];
    s += v; q += v*v;
  }
  __shared__ float ls[256], lq[256];
  ls[threadIdx.x] = s; lq[threadIdx.x] = q;
  __syncthreads();
  if (rl == 0){
    int tt = threadIdx.x;
    psum[blockIdx.y*C + c] = ls[tt] + ls[tt+64] + ls[tt+128] + ls[tt+192];
    psq [blockIdx.y*C + c] = lq[tt] + lq[tt+64] + lq[tt+128] + lq[tt+192];
  }
}
__global__ void k_bn_stats(const float* __restrict__ psum, const float* __restrict__ psq,
                           int C, float* __restrict__ stat){
  int c = blockIdx.x*256 + threadIdx.x; if (c >= C) return;
  float s = 0.f, q = 0.f;
  for (int ch=0; ch<32; ch++){ s += psum[ch*C + c]; q += psq[ch*C + c]; }
  float m = s * (1.f/16384.f);
  float var = q * (1.f/16384.f) - m*m;
  stat[c] = m;
  stat[C + c] = rsqrtf(var + 1e-5f);
}
// writes lrelu(bn(x),0.2) as h/m into Oh/Om at [row*ldo + co + c]
__global__ void k_bn_apply(const float* __restrict__ X, int Cshift, int C,
                           const float* __restrict__ stat,
                           const float* __restrict__ g, const float* __restrict__ b,
                           u16* __restrict__ Oh, u16* __restrict__ Om,
                           int ldo, int co, int total){
  for (int idx = blockIdx.x*256 + threadIdx.x; idx < total; idx += gridDim.x*256){
    int c = idx & (C-1);
    int r = idx >> Cshift;
    float v = (X[idx] - stat[c]) * stat[C + c] * g[c] + b[c];
    v = (v >= 0.f) ? v : 0.2f*v;
    size_t o = (size_t)r*ldo + co + c;
    u16 h = f2b(v); Oh[o] = h;
    Om[o] = f2b(v - b2f(h));
  }
}

// ---------------- host ----------------
extern "C" void kernel_launch(void* const* d_in, const int* in_sizes, int n_in,
                              void* d_out, int out_size, void* d_ws, size_t ws_size,
                              hipStream_t stream) {
  (void)in_sizes; (void)n_in; (void)out_size; (void)ws_size;
  const float* x0   = (const float*)d_in[0];
  const float* ea   = (const float*)d_in[1];
  const int*   ei   = (const int*)d_in[2];
  const float* f1_g = (const float*)d_in[23];
  const float* f1_b = (const float*)d_in[24];
  const float* f2_g1= (const float*)d_in[26];
  const float* f2_b1= (const float*)d_in[27];
  const float* f2_g2= (const float*)d_in[29];
  const float* f2_b2= (const float*)d_in[30];
  float* out = (float*)d_out;

  const float* wsrc[22] = {
    (const float*)d_in[4],(const float*)d_in[5],(const float*)d_in[6],(const float*)d_in[7],
    (const float*)d_in[8],(const float*)d_in[9],(const float*)d_in[10],(const float*)d_in[11],
    (const float*)d_in[12],(const float*)d_in[13],(const float*)d_in[14],(const float*)d_in[15],
    (const float*)d_in[16],(const float*)d_in[17],(const float*)d_in[18],
    (const float*)d_in[19],(const float*)d_in[20],(const float*)d_in[21],
    (const float*)d_in[22],(const float*)d_in[25],(const float*)d_in[28],(const float*)d_in[31]
  };
  const int wK[22] = {128,96,64,64, 128,128,128,64, 192,192,192,128,
                      128,128,64, 256,192,128, 704, 1728, 512, 256};
  const int wN[22] = {96,64,64,64, 128,128,128,128, 192,192,192,192,
                      128,128,128, 192,192,192, 1024, 512, 256, 128};
  int wNp[22];
  for (int i=0;i<22;i++) wNp[i] = (wN[i] + 127) & ~127;

  char* w = (char*)d_ws;
  size_t off = 0;
  auto alloc = [&](size_t bytes)->char*{
    char* p = w + off; off = (off + bytes + 255) & ~(size_t)255; return p;
  };
  // fp32 persistents
  float* sg1f = (float*)alloc((size_t)NN*64*4);
  float* sg2f = (float*)alloc((size_t)NN*128*4);
  float* dg1f = (float*)alloc((size_t)NN*128*4);
  // cat1 split store: cols [sg1 0:64 | dg1 64:192 | dg2 192:384 | sg2 384:512 | sg3 512:704]
  u16* cat1h = (u16*)alloc((size_t)NN*704*2);
  u16* cat1m = (u16*)alloc((size_t)NN*704*2);
  u16* sg1l  = (u16*)alloc((size_t)NN*64*2);
  u16* dg1l  = (u16*)alloc((size_t)NN*128*2);
  float* bnp  = (float*)alloc((size_t)2*32*1024*4);
  float* bns  = (float*)alloc((size_t)2*1024*4);
  u16 *wh[22], *wm[22], *wl[22];
  for (int i=0;i<22;i++){
    size_t e = (size_t)wK[i]*wNp[i];
    wh[i] = (u16*)alloc(e*2); wm[i] = (u16*)alloc(e*2); wl[i] = (u16*)alloc(e*2);
  }
  char* arena = alloc((size_t)120*1024*1024);
  size_t ac = 0;
  auto aalloc = [&](size_t b)->char*{
    char* p = arena + ac; ac = (ac + b + 255) & ~(size_t)255; return p;
  };

  auto MG = [&](int P, const u16* Ah, const u16* Am, const u16* Al, int lda, int ldal,
                const u16* Bh, const u16* Bm, const u16* Bl, int ldb,
                float* Cf, u16* Ch, u16* Cm, u16* Cl, int ldc, int ldsp, int cosp, int ldspl,
                int M, int K, int Nc, float slope, int flags, int colbase){
    dim3 g((Nc+127)/128, M/128);
    if (P == 3)
      k_mgemm<3,0><<<g,256,0,stream>>>(Ah,Am,Al,lda,ldal,Bh,Bm,Bl,ldb,
        Cf,Ch,Cm,Cl,ldc,ldsp,cosp,ldspl,K,Nc,slope,flags,colbase,nullptr,nullptr,0,0);
    else
      k_mgemm<2,0><<<g,256,0,stream>>>(Ah,Am,Al,lda,ldal,Bh,Bm,Bl,ldb,
        Cf,Ch,Cm,Cl,ldc,ldsp,cosp,ldspl,K,Nc,slope,flags,colbase,nullptr,nullptr,0,0);
  };
  auto MGG = [&](int P, const float* Xf, const int* topig, int c0g, int Dxg,
                 const u16* Bh, const u16* Bm, const u16* Bl, int ldb,
                 u16* Ch, u16* Cm, u16* Cl, int ldsp, int ldspl,
                 int M, int Nc, float slope){
    dim3 g((Nc+127)/128, M/128);
    if (P == 3)
      k_mgemm<3,1><<<g,256,0,stream>>>(nullptr,nullptr,nullptr,0,0,Bh,Bm,Bl,ldb,
        nullptr,Ch,Cm,Cl,0,ldsp,0,ldspl,2*Dxg,Nc,slope,0,0,Xf,topig,c0g,Dxg);
    else
      k_mgemm<2,1><<<g,256,0,stream>>>(nullptr,nullptr,nullptr,0,0,Bh,Bm,Bl,ldb,
        nullptr,Ch,Cm,Cl,0,ldsp,0,ldspl,2*Dxg,Nc,slope,0,0,Xf,topig,c0g,Dxg);
  };

  // -------- weight prep (padded) --------
  for (int i=0;i<22;i++){
    int e = wK[i]*wNp[i];
    k_wprep3<<<(e+255)/256, 256, 0, stream>>>(wsrc[i], wK[i], wN[i], wNp[i], wh[i], wm[i], wl[i]);
  }

  // -------- static-phase arena --------
  ac = 0;
  u16* t1s[3]; for (int c=0;c<3;c++) t1s[c] = (u16*)aalloc((size_t)NN*192*2);
  u16* t2s[3]; for (int c=0;c<3;c++) t2s[c] = (u16*)aalloc((size_t)NN*192*2);
  float* sof32 = (float*)aalloc((size_t)NN*192*4);
  int* csr_cnt = (int*)aalloc((size_t)NN*4);
  int* csr_off = (int*)aalloc((size_t)(NN+1)*4);
  int* csr_src = (int*)aalloc((size_t)NE*4);
  int* csr_eid = (int*)aalloc((size_t)NE*4);
  u16* x0s[3]; for (int c=0;c<3;c++) x0s[c] = (u16*)aalloc((size_t)NN*64*2);

  k_split3<<<(NN*64+255)/256, 256, 0, stream>>>(x0, x0s[0], x0s[1], x0s[2], NN*64, 64, 64, 0, 64);

  // -------- CSR build --------
  const int* srcp = ei;
  const int* dstp = ei + NE;
  k_fill_i32<<<(NN+255)/256, 256, 0, stream>>>(csr_cnt, 0, NN);
  k_hist<<<NE/256, 256, 0, stream>>>(dstp, csr_cnt);
  k_scan<<<1, 1024, 0, stream>>>(csr_cnt, csr_off);
  k_fill_i32<<<(NN+255)/256, 256, 0, stream>>>(csr_cnt, 0, NN);
  k_csr_fill<<<NE/256, 256, 0, stream>>>(srcp, dstp, csr_off, csr_cnt, csr_src, csr_eid);

  // -------- static layers --------
  auto static_layer = [&](int P, const float* xf,
                          const u16* xh, const u16* xm, const u16* xl, int lda, int ldal,
                          int Dx, int wi, float* of, int co, u16* lout, int H1, int H2){
    int DM = Dx + 64;
    k_static_segmax<<<NN, DM, 0, stream>>>(xf, Dx, ea, csr_off, csr_src, csr_eid,
                                           t1s[0], t1s[1], t1s[2]);
    MG(P, t1s[0],t1s[1],t1s[2], DM,DM, wh[wi],wm[wi],wl[wi], DM,
       nullptr, t2s[0],t2s[1],t2s[2], 0, H1,0,H1, NN, DM, H1, 0.1f, 0, 0);
    MG(P, t2s[0],t2s[1],t2s[2], H1,H1, wh[wi+1],wm[wi+1],wl[wi+1], H1,
       nullptr, t1s[0],t1s[1],t1s[2], 0, H2,0,H2, NN, H1, H2, 0.1f, 0, 0);
    MG(P, xh,xm,xl, lda,ldal, wh[wi+3],wm[wi+3],wl[wi+3], Dx,
       of, nullptr,nullptr,nullptr, H2,0,0,0, NN, Dx, H2, 0.1f, 0, 0);          // of = lrelu(x@lin)
    MG(P, t1s[0],t1s[1],t1s[2], H2,H2, wh[wi+2],wm[wi+2],wl[wi+2], H2,
       of, cat1h,cat1m,lout, H2, 704,co,(lout? (co==0?64:128) : 0),
       NN, H2, H2, 0.1f, 1, 0);                                                  // of += lrelu(h@w3)
  };
  static_layer(3, x0,  x0s[0],x0s[1],x0s[2], 64,64, 64, 0, sg1f, 0,   sg1l, 96, 64);
  static_layer(2, sg1f, cat1h+0,  cat1m+0,  nullptr, 704,0, 64, 4, sg2f, 384, nullptr, 128, 128);
  static_layer(2, sg2f, cat1h+384,cat1m+384,nullptr, 704,0, 128,8, sof32,512, nullptr, 192, 192);

  // -------- dynamic-phase arena --------
  ac = 0;
  u16* xns[3]; for (int c=0;c<3;c++) xns[c] = (u16*)aalloc((size_t)NN*128*2);
  float* topv = (float*)aalloc((size_t)NN*16*4);
  int*   topi = (int*)aalloc((size_t)NN*16*4);
  float* dg2of = (float*)aalloc((size_t)NN*192*4);
  size_t dyn0 = ac;

  auto dyn_layer = [&](int P, const float* xf,
                       const u16* xh, const u16* xm, const u16* xl, int lda, int ldal,
                       int Dx, int wi, float* ofp, int co, u16* lout, int H1, int H2, int nch){
    const int R = nch*KEDGE;   // mult of 128
    ac = dyn0;
    float* S = (float*)aalloc((size_t)NN*SCC*4);
    ac = dyn0;   // alias: S dead once topk loop finishes
    u16* mms[3]; for (int c=0;c<3;c++) mms[c] = (u16*)aalloc((size_t)R*H1*2);
    float* mout = (float*)aalloc((size_t)R*H2*4);

    k_normalize<<<NN, 64, 0, stream>>>(xf, xns[0], xns[1], xns[2], Dx);
    for (int cb = 0; cb < NN; cb += SCC){
      MG(3, xns[0],xns[1],xns[2], Dx,Dx,
         xns[0]+(size_t)cb*Dx, xns[1]+(size_t)cb*Dx, xns[2]+(size_t)cb*Dx, Dx,
         S, nullptr,nullptr,nullptr, SCC,0,0,0, NN, Dx, SCC, 1.0f, 2, cb);
      k_topk_merge<<<NN/4, 256, 0, stream>>>(S, cb, topv, topi, cb == 0);
    }
    MG(P, xh,xm,xl, lda,ldal, wh[wi+2],wm[wi+2],wl[wi+2], Dx,
       ofp, nullptr,nullptr,nullptr, H2,0,0,0, NN, Dx, H2, 0.1f, 0, 0);   // ofp = lrelu(x@lin)
    for (int c0 = 0; c0 < NN; c0 += nch){
      MGG(P, xf, topi, c0, Dx, wh[wi],wm[wi],wl[wi], 2*Dx,
          mms[0],mms[1],(P==3?mms[2]:nullptr), H1,H1, R, H1, 0.2f);
      MG(P, mms[0],mms[1],mms[2], H1,H1, wh[wi+1],wm[wi+1],wl[wi+1], H1,
         mout, nullptr,nullptr,nullptr, H2,0,0,0, R, H1, H2, 0.2f, 0, 0);
      k_segmax_add<<<nch, H2, 0, stream>>>(mout, H2, c0, ofp);            // ofp += segmax
    }
    k_split3<<<(NN*H2+255)/256, 256, 0, stream>>>(ofp, cat1h, cat1m, lout,
                                                  NN*H2, H2, 704, co, H2);
  };
  dyn_layer(3, sg1f, cat1h+0, cat1m+0, sg1l, 704,64, 64,  12, dg1f, 64,  dg1l, 128, 128, 4096);
  dyn_layer(2, dg1f, cat1h+64,cat1m+64,nullptr,704,0, 128, 15, dg2of,192, nullptr,192, 192, 2048);

  // -------- fusion-phase arena --------
  ac = 0;
  u16*   f1sh = (u16*)aalloc((size_t)NN*1024*2);   // f1 splits [NN,1024]
  u16*   f1sm = (u16*)aalloc((size_t)NN*1024*2);
  float* fscr = (float*)aalloc((size_t)NN*512*4);  // fp32 scratch [NN,512]
  // aliases once producers are dead:
  u16* h2h = f1sh;
  u16* h2m = f1sm;
  float* h3f32 = (float*)(f1sm + (size_t)NN*512);
  u16* h3h = f1sh + (size_t)NN*512;
  u16* h3m = h3h + (size_t)NN*256;

  auto bn = [&](const float* X, int C, int Cshift, const float* g, const float* b,
                u16* Oh, u16* Om, int ldo, int co){
    k_bn_part<<<dim3(C/64, 32), 256, 0, stream>>>(X, C, bnp, bnp + 32*1024);
    k_bn_stats<<<(C+255)/256, 256, 0, stream>>>(bnp, bnp + 32*1024, C, bns);
    k_bn_apply<<<2048, 256, 0, stream>>>(X, Cshift, C, bns, g, b, Oh, Om, ldo, co, NN*C);
  };

  // f1 in two 512-col halves: fscr = cat1 @ f1_w[:, p*512:...] ; bn -> f1s
  for (int p = 0; p < 2; p++){
    MG(2, cat1h,cat1m,nullptr, 704,0, wh[18]+(size_t)p*512*704, wm[18]+(size_t)p*512*704, nullptr, 704,
       fscr, nullptr,nullptr,nullptr, 512,0,0,0, NN, 704, 512, 1.f, 0, 0);
    bn(fscr, 512, 9, f1_g + p*512, f1_b + p*512, f1sh, f1sm, 1024, p*512);
  }
  // h2 = lrelu(bn(cat2 @ f2_w1)) ; cat2 = [f1 | cat1]
  MG(2, f1sh,f1sm,nullptr, 1024,0, wh[19],wm[19],nullptr, 1728,
     fscr, nullptr,nullptr,nullptr, 512,0,0,0, NN, 1024, 512, 1.f, 0, 0);
  MG(2, cat1h,cat1m,nullptr, 704,0, wh[19]+1024,wm[19]+1024,nullptr, 1728,
     fscr, nullptr,nullptr,nullptr, 512,0,0,0, NN, 704, 512, 1.f, 1, 0);
  bn(fscr, 512, 9, f2_g1, f2_b1, h2h, h2m, 512, 0);
  MG(2, h2h,h2m,nullptr, 512,0, wh[20],wm[20],nullptr, 512,
     h3f32, nullptr,nullptr,nullptr, 256,0,0,0, NN, 512, 256, 1.f, 0, 0);
  bn(h3f32, 256, 8, f2_g2, f2_b2, h3h, h3m, 256, 0);
  MG(2, h3h,h3m,nullptr, 256,0, wh[21],wm[21],nullptr, 256,
     out, nullptr,nullptr,nullptr, 128,0,0,0, NN, 256, 128, 1.f, 0, 0);
}

// Round 16
// 4288.066 us; speedup vs baseline: 1.4946x; 1.0014x over previous
//
#include <hip/hip_runtime.h>
#include <math.h>

typedef unsigned short u16;
typedef unsigned int u32;
typedef unsigned long long u64;
typedef __attribute__((ext_vector_type(8))) short short8v;
typedef __attribute__((ext_vector_type(4))) float f32x4;

static const int NN  = 16384;
static const int NE  = 524288;
static const int SCC = 1024;   // sim column chunk
static const int KEDGE = 17;

__device__ __forceinline__ u16 f2b(float v){
  u32 u = __float_as_uint(v);
  u += 0x7FFFu + ((u >> 16) & 1u);
  return (u16)(u >> 16);
}
__device__ __forceinline__ float b2f(u16 h){ return __uint_as_float(((u32)h) << 16); }

// async 16B global->LDS (gfx950). LDS dest is wave-uniform base + lane*16.
__device__ __forceinline__ void gl_lds16(const u16* g, u16* l){
  __builtin_amdgcn_global_load_lds(
      (const __attribute__((address_space(1))) u32*)(g),
      (__attribute__((address_space(3))) u32*)(l), 16, 0, 0);
}

// ---------------- utility ----------------
__global__ void k_fill_i32(int* p, int v, int n){
  int i = blockIdx.x*256 + threadIdx.x; if (i < n) p[i] = v;
}
// fp32 [n] (rows of C) -> h/m at [r*ldo+co+c], l (optional) at [r*ldl+c]
__global__ void k_split3(const float* __restrict__ s, u16* __restrict__ h,
                         u16* __restrict__ m, u16* __restrict__ l, int n,
                         int C, int ldo, int co, int ldl){
  int i = blockIdx.x*256 + threadIdx.x; if (i >= n) return;
  int r = i / C, c = i % C;
  float v = s[i];
  u16 hh = f2b(v);
  float rr = v - b2f(hh);
  u16 mm_ = f2b(rr);
  size_t o = (size_t)r*ldo + co + c;
  h[o] = hh; m[o] = mm_;
  if (l) l[(size_t)r*ldl + c] = f2b(rr - b2f(mm_));
}
// W [K,N] fp32 -> Wt [Npad,K] 3-way split, zero rows for n >= N
__global__ void k_wprep3(const float* __restrict__ W, int K, int N, int Npad,
                         u16* __restrict__ h, u16* __restrict__ m, u16* __restrict__ l){
  int idx = blockIdx.x*256 + threadIdx.x; if (idx >= K*Npad) return;
  int n = idx / K, k = idx % K;
  float v = (n < N) ? W[(size_t)k*N + n] : 0.f;
  u16 hh = f2b(v); h[idx] = hh;
  float r = v - b2f(hh);
  u16 mm_ = f2b(r); m[idx] = mm_;
  l[idx] = f2b(r - b2f(mm_));
}

// ---------------- CSR build ----------------
__global__ void k_hist(const int* __restrict__ dst, int* __restrict__ cnt){
  int e = blockIdx.x*256 + threadIdx.x; if (e < NE) atomicAdd(&cnt[dst[e]], 1);
}
__global__ void k_scan(const int* __restrict__ cnt, int* __restrict__ off){
  __shared__ int part[1024];
  int t = threadIdx.x;
  int base = t*16;
  int loc[16]; int s = 0;
#pragma unroll
  for (int q=0;q<16;q++){ loc[q] = s; s += cnt[base+q]; }
  part[t] = s; __syncthreads();
  for (int d=1; d<1024; d<<=1){
    int v = (t>=d) ? part[t-d] : 0; __syncthreads();
    part[t] += v; __syncthreads();
  }
  int prev = (t==0) ? 0 : part[t-1];
#pragma unroll
  for (int q=0;q<16;q++) off[base+q] = prev + loc[q];
  if (t == 1023) off[NN] = part[1023];
}
__global__ void k_csr_fill(const int* __restrict__ src, const int* __restrict__ dst,
                           const int* __restrict__ off, int* __restrict__ cur,
                           int* __restrict__ csrc, int* __restrict__ ceid){
  int e = blockIdx.x*256 + threadIdx.x; if (e >= NE) return;
  int d = dst[e];
  int p = atomicAdd(&cur[d], 1);
  int idx = off[d] + p;
  csrc[idx] = src[e];
  ceid[idx] = e;
}

// ---------------- static segment-max (fp32 in, split3 out) ----------------
__global__ void k_static_segmax(const float* __restrict__ x, int Dx,
                                const float* __restrict__ ea,
                                const int* __restrict__ off,
                                const int* __restrict__ csrc,
                                const int* __restrict__ ceid,
                                u16* __restrict__ th, u16* __restrict__ tm,
                                u16* __restrict__ tl){
  int i = blockIdx.x, c = threadIdx.x;
  int DM = Dx + 64;
  int s = off[i], e = off[i+1];
  float mx = -INFINITY;
  float v;
  if (c < Dx){
    for (int t = s; t < e; t++) mx = fmaxf(mx, x[(size_t)csrc[t]*Dx + c]);
    v = (s == e) ? 0.f : (mx - x[(size_t)i*Dx + c]);
  } else {
    int cc = c - Dx;
    for (int t = s; t < e; t++) mx = fmaxf(mx, ea[(size_t)ceid[t]*64 + cc]);
    v = (s == e) ? 0.f : mx;
  }
  size_t o = (size_t)i*DM + c;
  u16 h = f2b(v); th[o] = h;
  float r = v - b2f(h);
  u16 mm_ = f2b(r); tm[o] = mm_;
  tl[o] = f2b(r - b2f(mm_));
}

// ---------------- MFMA GEMM over 3-way splits (global_load_lds staging) -------
// (round-7 form; no swizzle, no Smax epilogue)
template<int P, int GATHER>
__global__ __launch_bounds__(256) void k_mgemm(
    const u16* __restrict__ Ah, const u16* __restrict__ Am, const u16* __restrict__ Al,
    int lda, int ldal,
    const u16* __restrict__ Bh, const u16* __restrict__ Bm, const u16* __restrict__ Bl,
    int ldb,
    float* __restrict__ Cf, u16* __restrict__ Ch, u16* __restrict__ Cm, u16* __restrict__ Cl,
    int ldc, int ldsp, int cosp, int ldspl,
    int K, int Nc, float slope, int flags, int colbase,
    const float* __restrict__ Xf, const int* __restrict__ topig, int c0g, int Dxg)
{
  constexpr int NC = (P == 3) ? 3 : 2;
  __shared__ u16 lds[NC*2*4096];
  const int t = threadIdx.x;
  const int m0 = blockIdx.y * 128, n0 = blockIdx.x * 128;
  const int wave = t >> 6, lane = t & 63;
  const int wr = (wave >> 1) << 6, wc = (wave & 1) << 6;
  const int l15 = lane & 15, l4 = lane >> 4;
  f32x4 acc[4][4] = {};

  const u16* Ap[3] = {Ah, Am, Al};
  const int ldav[3] = {lda, lda, ldal};
  const u16* Bp[3] = {Bh, Bm, Bl};

  const int c0c = wave*128 + lane, c1c = c0c + 64;
  const int r0c = c0c & 127, s0c = c0c >> 7;
  const int r1c = c1c & 127, s1c = c1c >> 7;
  const int lb0 = (wave*128)*8;
  const int lb1 = (wave*128 + 64)*8;

  size_t gA0[3], gA1[3], gB0[3], gB1[3];
#pragma unroll
  for (int cc=0; cc<NC; cc++){
    if (!GATHER){
      gA0[cc] = (size_t)(m0 + r0c)*ldav[cc] + s0c*8;
      gA1[cc] = (size_t)(m0 + r1c)*ldav[cc] + s1c*8;
    }
    gB0[cc] = (size_t)(n0 + r0c)*ldb + s0c*8;
    gB1[cc] = (size_t)(n0 + r1c)*ldb + s1c*8;
  }

  const int sr = t & 127, sseg = t >> 7;
  int node_i = 0, node_j = 0;
  if (GATHER){
    int erow = m0 + sr;
    int i = c0g + erow / KEDGE;
    int slot = erow % KEDGE;
    node_i = i;
    node_j = (slot < 16) ? topig[i*16 + slot] : i;
  }

  for (int k0 = 0; k0 < K; k0 += 32){
    __attribute__((aligned(16))) u16 hb[16], mb[16], lcb[16];
    if (GATHER){
      int kpos = k0 + sseg*16;
      bool side = kpos < Dxg;
      int kk = side ? kpos : kpos - Dxg;
      const float* xi = Xf + (size_t)node_i*Dxg + kk;
      const float* xj = Xf + (size_t)node_j*Dxg + kk;
#pragma unroll
      for (int q4=0;q4<4;q4++){
        float4 a = *(const float4*)(xi + q4*4);
        if (!side){
          float4 b = *(const float4*)(xj + q4*4);
          a = make_float4(b.x-a.x, b.y-a.y, b.z-a.z, b.w-a.w);
        }
        float vv[4] = {a.x, a.y, a.z, a.w};
#pragma unroll
        for (int q=0;q<4;q++){
          float v = vv[q];
          u16 h = f2b(v); hb[q4*4+q] = h;
          float r = v - b2f(h);
          u16 mm_ = f2b(r); mb[q4*4+q] = mm_;
          if (NC == 3) lcb[q4*4+q] = f2b(r - b2f(mm_));
        }
      }
    }
    __syncthreads();
    if (GATHER){
      int base0 = (sseg*2)*1024 + sr*8;
      int base1 = (sseg*2+1)*1024 + sr*8;
      *(int4*)&lds[0*4096 + base0] = *(const int4*)&hb[0];
      *(int4*)&lds[0*4096 + base1] = *(const int4*)&hb[8];
      *(int4*)&lds[1*4096 + base0] = *(const int4*)&mb[0];
      *(int4*)&lds[1*4096 + base1] = *(const int4*)&mb[8];
      if (NC == 3){
        *(int4*)&lds[2*4096 + base0] = *(const int4*)&lcb[0];
        *(int4*)&lds[2*4096 + base1] = *(const int4*)&lcb[8];
      }
    } else {
#pragma unroll
      for (int cc=0; cc<NC; cc++){
        gl_lds16(Ap[cc] + gA0[cc] + k0, &lds[cc*4096 + lb0]);
        gl_lds16(Ap[cc] + gA1[cc] + k0, &lds[cc*4096 + lb1]);
      }
    }
#pragma unroll
    for (int cc=0; cc<NC; cc++){
      gl_lds16(Bp[cc] + gB0[cc] + k0, &lds[(NC+cc)*4096 + lb0]);
      gl_lds16(Bp[cc] + gB1[cc] + k0, &lds[(NC+cc)*4096 + lb1]);
    }
    __syncthreads();
    short8v fa[NC][4], fb[NC][4];
#pragma unroll
    for (int m=0;m<4;m++){
      int ra = l4*1024 + (wr + m*16 + l15)*8;
      int rb = l4*1024 + (wc + m*16 + l15)*8;
#pragma unroll
      for (int cc=0;cc<NC;cc++){
        fa[cc][m] = *(const short8v*)&lds[cc*4096 + ra];
        fb[cc][m] = *(const short8v*)&lds[(NC+cc)*4096 + rb];
      }
    }
#pragma unroll
    for (int m=0;m<4;m++)
#pragma unroll
      for (int n=0;n<4;n++){
        if (P == 3){
          acc[m][n] = __builtin_amdgcn_mfma_f32_16x16x32_bf16(fa[1][m], fb[1][n], acc[m][n], 0,0,0);
          acc[m][n] = __builtin_amdgcn_mfma_f32_16x16x32_bf16(fa[0][m], fb[2][n], acc[m][n], 0,0,0);
          acc[m][n] = __builtin_amdgcn_mfma_f32_16x16x32_bf16(fa[2][m], fb[0][n], acc[m][n], 0,0,0);
        }
        acc[m][n] = __builtin_amdgcn_mfma_f32_16x16x32_bf16(fa[0][m], fb[1][n], acc[m][n], 0,0,0);
        acc[m][n] = __builtin_amdgcn_mfma_f32_16x16x32_bf16(fa[1][m], fb[0][n], acc[m][n], 0,0,0);
        acc[m][n] = __builtin_amdgcn_mfma_f32_16x16x32_bf16(fa[0][m], fb[0][n], acc[m][n], 0,0,0);
      }
  }

  const float NEG = -__builtin_inff();
#pragma unroll
  for (int n=0;n<4;n++){
    int col0 = n0 + wc + n*16;
    if (col0 >= Nc) continue;
    int col = col0 + l15;
#pragma unroll
    for (int m=0;m<4;m++){
      int rowb = m0 + wr + m*16 + l4*4;
#pragma unroll
      for (int r=0;r<4;r++){
        int row = rowb + r;
        float v = acc[m][n][r];
        if ((flags & 2) && row == colbase + col) v = NEG;
        else v = (v >= 0.f) ? v : v*slope;
        if (col < Nc){
          if (flags & 1) v += Cf[(size_t)row*ldc + col];
          if (Cf) Cf[(size_t)row*ldc + col] = v;
          if (Ch){
            size_t o = (size_t)row*ldsp + cosp + col;
            u16 h = f2b(v); Ch[o] = h;
            float rr = v - b2f(h);
            u16 mm_ = f2b(rr); Cm[o] = mm_;
            if (Cl) Cl[(size_t)row*ldspl + col] = f2b(rr - b2f(mm_));
          }
        }
      }
    }
  }
}

// ---------------- kNN pieces ----------------
__global__ void k_normalize(const float* __restrict__ x,
                            u16* __restrict__ oh, u16* __restrict__ om,
                            u16* __restrict__ ol, int Dx){
  int i = blockIdx.x, lane = threadIdx.x;   // 64 lanes
  size_t o0 = (size_t)i*Dx + lane;
  float a = x[o0];
  float b = 0.f;
  if (Dx == 128) b = x[o0 + 64];
  float ss = a*a + b*b;
  for (int d = 32; d; d >>= 1) ss += __shfl_xor(ss, d);
  float rs = rsqrtf(ss + 1e-12f);
  float va = a*rs;
  u16 h = f2b(va); oh[o0] = h;
  float r = va - b2f(h);
  u16 mm_ = f2b(r); om[o0] = mm_;
  ol[o0] = f2b(r - b2f(mm_));
  if (Dx == 128){
    float vb = b*rs;
    u16 h2 = f2b(vb); oh[o0+64] = h2;
    float r2 = vb - b2f(h2);
    u16 m2 = f2b(r2); om[o0+64] = m2;
    ol[o0+64] = f2b(r2 - b2f(m2));
  }
}

// 4 rows per block (4 waves). Running top-16 SORTED (value desc, index asc)
// in lanes 0..15. Optionally scans TWO chunks (S1 != null, cols colbase+SCC..)
// in one launch — union selection is order-invariant, so pairing is exact.
// first: seed exactly from S0's 1024 candidates (16-round selection), then
// threshold-insert S1. Otherwise threshold-insert S0 then S1 (R10 fast path:
// per-round ballot gate + sorted insert with live-threshold re-check).
// tie-break: larger value, then smaller index (matches jax.lax.top_k).
__global__ void k_topk_merge(const float* __restrict__ S0,
                             const float* __restrict__ S1, int colbase,
                             float* __restrict__ topv, int* __restrict__ topi,
                             int first){
  const float INF = __builtin_inff();
  int i = blockIdx.x*4 + (threadIdx.x >> 6);
  int lane = threadIdx.x & 63;

  float pv = -INF; int pj = 0x7fffffff;
  bool store = false;

  if (first){
    const float* row = S0 + (size_t)i * SCC;
    float cv[16]; int cj[16];
#pragma unroll
    for (int r4=0;r4<4;r4++){
      int cb = r4*256 + lane*4;
      float4 v4 = *(const float4*)(row + cb);
      float vv[4] = {v4.x, v4.y, v4.z, v4.w};
#pragma unroll
      for (int q=0;q<4;q++){
        int j = colbase + cb + q;
        float v = vv[q];
        if (j == i) v = -INF;
        cv[r4*4+q] = v; cj[r4*4+q] = j;
      }
    }
    float myv = -INF; int myj = 0x7fffffff;
#pragma unroll
    for (int r=0;r<16;r++){
      float lv = -INF; int lj = 0x7fffffff;
#pragma unroll
      for (int q=0;q<16;q++){
        bool better = (cv[q] > lv) || (cv[q] == lv && cj[q] < lj);
        if (better){ lv = cv[q]; lj = cj[q]; }
      }
      float bv = lv; int bj = lj;
      for (int d=32; d; d>>=1){
        float ov = __shfl_xor(bv, d);
        int oj = __shfl_xor(bv == ov ? bj : bj, d);   // placeholder avoided below
        (void)oj;
        int oj2 = __shfl_xor(bj, d);
        bool better = (ov > bv) || (ov == bv && oj2 < bj);
        if (better){ bv = ov; bj = oj2; }
      }
#pragma unroll
      for (int q=0;q<16;q++) if (cj[q] == bj) cv[q] = -INF;
      if (lane == r){ myv = bv; myj = bj; }
    }
    if (lane < 16){ pv = myv; pj = myj; }
    store = true;
  } else {
    if (lane < 16){ pv = topv[i*16+lane]; pj = topi[i*16+lane]; }
  }
  float tv = __shfl(pv, 15); int tj = __shfl(pj, 15);

  auto scan = [&](const float* Sb, int cbase){
    const float* row = Sb + (size_t)i * SCC;
#pragma unroll
    for (int r4=0; r4<4; r4++){
      int cb = r4*256 + lane*4;
      float4 v4 = *(const float4*)(row + cb);
      float vv[4] = {v4.x, v4.y, v4.z, v4.w};
      int js[4]; bool sv[4]; bool any = false;
#pragma unroll
      for (int q=0;q<4;q++){
        int j = cbase + cb + q;
        float v = vv[q];
        if (j == i) v = -INF;
        vv[q] = v; js[q] = j;
        sv[q] = (v > tv) || (v == tv && j < tj);
        any |= sv[q];
      }
      if (__ballot(any) == 0) continue;
#pragma unroll
      for (int q=0;q<4;q++){
        u64 msk = __ballot(sv[q]);
        while (msk){
          int src = __ffsll((long long)msk) - 1; msk &= msk - 1;
          float v = __shfl(vv[q], src);
          int   j = __shfl(js[q], src);
          if ((v > tv) || (v == tv && j < tj)){        // re-check vs live thr
            bool eb = (pv > v) || (pv == v && pj < j);
            u32 mb = (u32)__ballot(eb) & 0xFFFFu;
            int p = __popc(mb);
            float svv = __shfl_up(pv, 1); int sjj = __shfl_up(pj, 1);
            if (lane < 16 && lane >= p){
              if (lane == p){ pv = v; pj = j; }
              else          { pv = svv; pj = sjj; }
            }
            tv = __shfl(pv, 15); tj = __shfl(pj, 15);
            store = true;
          }
        }
      }
    }
  };
  if (!first) scan(S0, colbase);
  if (S1)     scan(S1, colbase + SCC);
  if (store && lane < 16){ topv[i*16+lane] = pv; topi[i*16+lane] = pj; }
}

// ---------------- dynamic layer pieces ----------------
__global__ void k_segmax_add(const float* __restrict__ mo, int H2, int c0,
                             float* __restrict__ outp){
  int ii = blockIdx.x;
  int c = threadIdx.x;
  float m = -INFINITY;
  for (int s=0;s<KEDGE;s++) m = fmaxf(m, mo[(size_t)(ii*KEDGE+s)*H2 + c]);
  outp[(size_t)(c0+ii)*H2 + c] += m;
}

// ---------------- BN ----------------
__global__ void k_bn_part(const float* __restrict__ X, int C,
                          float* __restrict__ psum, float* __restrict__ psq){
  int c = blockIdx.x*64 + (threadIdx.x & 63);
  int rl = threadIdx.x >> 6;
  int r0 = blockIdx.y * 512;
  float s = 0.f, q = 0.f;
  for (int r = r0 + rl; r < r0 + 512; r += 4){
    float v = X[(size_t)r*C + c];
    s += v; q += v*v;
  }
  __shared__ float ls[256], lq[256];
  ls[threadIdx.x] = s; lq[threadIdx.x] = q;
  __syncthreads();
  if (rl == 0){
    int tt = threadIdx.x;
    psum[blockIdx.y*C + c] = ls[tt] + ls[tt+64] + ls[tt+128] + ls[tt+192];
    psq [blockIdx.y*C + c] = lq[tt] + lq[tt+64] + lq[tt+128] + lq[tt+192];
  }
}
__global__ void k_bn_stats(const float* __restrict__ psum, const float* __restrict__ psq,
                           int C, float* __restrict__ stat){
  int c = blockIdx.x*256 + threadIdx.x; if (c >= C) return;
  float s = 0.f, q = 0.f;
  for (int ch=0; ch<32; ch++){ s += psum[ch*C + c]; q += psq[ch*C + c]; }
  float m = s * (1.f/16384.f);
  float var = q * (1.f/16384.f) - m*m;
  stat[c] = m;
  stat[C + c] = rsqrtf(var + 1e-5f);
}
// writes lrelu(bn(x),0.2) as h/m into Oh/Om at [row*ldo + co + c]
__global__ void k_bn_apply(const float* __restrict__ X, int Cshift, int C,
                           const float* __restrict__ stat,
                           const float* __restrict__ g, const float* __restrict__ b,
                           u16* __restrict__ Oh, u16* __restrict__ Om,
                           int ldo, int co, int total){
  for (int idx = blockIdx.x*256 + threadIdx.x; idx < total; idx += gridDim.x*256){
    int c = idx & (C-1);
    int r = idx >> Cshift;
    float v = (X[idx] - stat[c]) * stat[C + c] * g[c] + b[c];
    v = (v >= 0.f) ? v : 0.2f*v;
    size_t o = (size_t)r*ldo + co + c;
    u16 h = f2b(v); Oh[o] = h;
    Om[o] = f2b(v - b2f(h));
  }
}

// ---------------- host ----------------
extern "C" void kernel_launch(void* const* d_in, const int* in_sizes, int n_in,
                              void* d_out, int out_size, void* d_ws, size_t ws_size,
                              hipStream_t stream) {
  (void)in_sizes; (void)n_in; (void)out_size;
  const float* x0   = (const float*)d_in[0];
  const float* ea   = (const float*)d_in[1];
  const int*   ei   = (const int*)d_in[2];
  const float* f1_g = (const float*)d_in[23];
  const float* f1_b = (const float*)d_in[24];
  const float* f2_g1= (const float*)d_in[26];
  const float* f2_b1= (const float*)d_in[27];
  const float* f2_g2= (const float*)d_in[29];
  const float* f2_b2= (const float*)d_in[30];
  float* out = (float*)d_out;

  const float* wsrc[22] = {
    (const float*)d_in[4],(const float*)d_in[5],(const float*)d_in[6],(const float*)d_in[7],
    (const float*)d_in[8],(const float*)d_in[9],(const float*)d_in[10],(const float*)d_in[11],
    (const float*)d_in[12],(const float*)d_in[13],(const float*)d_in[14],(const float*)d_in[15],
    (const float*)d_in[16],(const float*)d_in[17],(const float*)d_in[18],
    (const float*)d_in[19],(const float*)d_in[20],(const float*)d_in[21],
    (const float*)d_in[22],(const float*)d_in[25],(const float*)d_in[28],(const float*)d_in[31]
  };
  const int wK[22] = {128,96,64,64, 128,128,128,64, 192,192,192,128,
                      128,128,64, 256,192,128, 704, 1728, 512, 256};
  const int wN[22] = {96,64,64,64, 128,128,128,128, 192,192,192,192,
                      128,128,128, 192,192,192, 1024, 512, 256, 128};
  int wNp[22];
  for (int i=0;i<22;i++) wNp[i] = (wN[i] + 127) & ~127;

  char* w = (char*)d_ws;
  size_t off = 0;
  auto alloc = [&](size_t bytes)->char*{
    char* p = w + off; off = (off + bytes + 255) & ~(size_t)255; return p;
  };
  // fp32 persistents
  float* sg1f = (float*)alloc((size_t)NN*64*4);
  float* sg2f = (float*)alloc((size_t)NN*128*4);
  float* dg1f = (float*)alloc((size_t)NN*128*4);
  // cat1 split store: cols [sg1 0:64 | dg1 64:192 | dg2 192:384 | sg2 384:512 | sg3 512:704]
  u16* cat1h = (u16*)alloc((size_t)NN*704*2);
  u16* cat1m = (u16*)alloc((size_t)NN*704*2);
  u16* sg1l  = (u16*)alloc((size_t)NN*64*2);
  u16* dg1l  = (u16*)alloc((size_t)NN*128*2);
  float* bnp  = (float*)alloc((size_t)2*32*1024*4);
  float* bns  = (float*)alloc((size_t)2*1024*4);
  u16 *wh[22], *wm[22], *wl[22];
  for (int i=0;i<22;i++){
    size_t e = (size_t)wK[i]*wNp[i];
    wh[i] = (u16*)alloc(e*2); wm[i] = (u16*)alloc(e*2); wl[i] = (u16*)alloc(e*2);
  }
  // arena takes ALL remaining workspace (>=120MB proven by prior passing rounds)
  char* arena = w + off;
  const size_t ARENA_SZ = (ws_size > off) ? (ws_size - off) : 0;
  size_t ac = 0;
  auto aalloc = [&](size_t b)->char*{
    char* p = arena + ac; ac = (ac + b + 255) & ~(size_t)255; return p;
  };

  auto MG = [&](int P, const u16* Ah, const u16* Am, const u16* Al, int lda, int ldal,
                const u16* Bh, const u16* Bm, const u16* Bl, int ldb,
                float* Cf, u16* Ch, u16* Cm, u16* Cl, int ldc, int ldsp, int cosp, int ldspl,
                int M, int K, int Nc, float slope, int flags, int colbase){
    dim3 g((Nc+127)/128, M/128);
    if (P == 3)
      k_mgemm<3,0><<<g,256,0,stream>>>(Ah,Am,Al,lda,ldal,Bh,Bm,Bl,ldb,
        Cf,Ch,Cm,Cl,ldc,ldsp,cosp,ldspl,K,Nc,slope,flags,colbase,nullptr,nullptr,0,0);
    else
      k_mgemm<2,0><<<g,256,0,stream>>>(Ah,Am,Al,lda,ldal,Bh,Bm,Bl,ldb,
        Cf,Ch,Cm,Cl,ldc,ldsp,cosp,ldspl,K,Nc,slope,flags,colbase,nullptr,nullptr,0,0);
  };
  auto MGG = [&](int P, const float* Xf, const int* topig, int c0g, int Dxg,
                 const u16* Bh, const u16* Bm, const u16* Bl, int ldb,
                 u16* Ch, u16* Cm, u16* Cl, int ldsp, int ldspl,
                 int M, int Nc, float slope){
    dim3 g((Nc+127)/128, M/128);
    if (P == 3)
      k_mgemm<3,1><<<g,256,0,stream>>>(nullptr,nullptr,nullptr,0,0,Bh,Bm,Bl,ldb,
        nullptr,Ch,Cm,Cl,0,ldsp,0,ldspl,2*Dxg,Nc,slope,0,0,Xf,topig,c0g,Dxg);
    else
      k_mgemm<2,1><<<g,256,0,stream>>>(nullptr,nullptr,nullptr,0,0,Bh,Bm,Bl,ldb,
        nullptr,Ch,Cm,Cl,0,ldsp,0,ldspl,2*Dxg,Nc,slope,0,0,Xf,topig,c0g,Dxg);
  };

  // -------- weight prep (padded) --------
  for (int i=0;i<22;i++){
    int e = wK[i]*wNp[i];
    k_wprep3<<<(e+255)/256, 256, 0, stream>>>(wsrc[i], wK[i], wN[i], wNp[i], wh[i], wm[i], wl[i]);
  }

  // -------- static-phase arena --------
  ac = 0;
  u16* t1s[3]; for (int c=0;c<3;c++) t1s[c] = (u16*)aalloc((size_t)NN*192*2);
  u16* t2s[3]; for (int c=0;c<3;c++) t2s[c] = (u16*)aalloc((size_t)NN*192*2);
  float* sof32 = (float*)aalloc((size_t)NN*192*4);
  int* csr_cnt = (int*)aalloc((size_t)NN*4);
  int* csr_off = (int*)aalloc((size_t)(NN+1)*4);
  int* csr_src = (int*)aalloc((size_t)NE*4);
  int* csr_eid = (int*)aalloc((size_t)NE*4);
  u16* x0s[3]; for (int c=0;c<3;c++) x0s[c] = (u16*)aalloc((size_t)NN*64*2);

  k_split3<<<(NN*64+255)/256, 256, 0, stream>>>(x0, x0s[0], x0s[1], x0s[2], NN*64, 64, 64, 0, 64);

  // -------- CSR build --------
  const int* srcp = ei;
  const int* dstp = ei + NE;
  k_fill_i32<<<(NN+255)/256, 256, 0, stream>>>(csr_cnt, 0, NN);
  k_hist<<<NE/256, 256, 0, stream>>>(dstp, csr_cnt);
  k_scan<<<1, 1024, 0, stream>>>(csr_cnt, csr_off);
  k_fill_i32<<<(NN+255)/256, 256, 0, stream>>>(csr_cnt, 0, NN);
  k_csr_fill<<<NE/256, 256, 0, stream>>>(srcp, dstp, csr_off, csr_cnt, csr_src, csr_eid);

  // -------- static layers --------
  auto static_layer = [&](int P, const float* xf,
                          const u16* xh, const u16* xm, const u16* xl, int lda, int ldal,
                          int Dx, int wi, float* of, int co, u16* lout, int H1, int H2){
    int DM = Dx + 64;
    k_static_segmax<<<NN, DM, 0, stream>>>(xf, Dx, ea, csr_off, csr_src, csr_eid,
                                           t1s[0], t1s[1], t1s[2]);
    MG(P, t1s[0],t1s[1],t1s[2], DM,DM, wh[wi],wm[wi],wl[wi], DM,
       nullptr, t2s[0],t2s[1],t2s[2], 0, H1,0,H1, NN, DM, H1, 0.1f, 0, 0);
    MG(P, t2s[0],t2s[1],t2s[2], H1,H1, wh[wi+1],wm[wi+1],wl[wi+1], H1,
       nullptr, t1s[0],t1s[1],t1s[2], 0, H2,0,H2, NN, H1, H2, 0.1f, 0, 0);
    MG(P, xh,xm,xl, lda,ldal, wh[wi+3],wm[wi+3],wl[wi+3], Dx,
       of, nullptr,nullptr,nullptr, H2,0,0,0, NN, Dx, H2, 0.1f, 0, 0);          // of = lrelu(x@lin)
    MG(P, t1s[0],t1s[1],t1s[2], H2,H2, wh[wi+2],wm[wi+2],wl[wi+2], H2,
       of, cat1h,cat1m,lout, H2, 704,co,(lout? (co==0?64:128) : 0),
       NN, H2, H2, 0.1f, 1, 0);                                                  // of += lrelu(h@w3)
  };
  static_layer(3, x0,  x0s[0],x0s[1],x0s[2], 64,64, 64, 0, sg1f, 0,   sg1l, 96, 64);
  static_layer(2, sg1f, cat1h+0,  cat1m+0,  nullptr, 704,0, 64, 4, sg2f, 384, nullptr, 128, 128);
  static_layer(2, sg2f, cat1h+384,cat1m+384,nullptr, 704,0, 128,8, sof32,512, nullptr, 192, 192);

  // -------- dynamic-phase arena --------
  ac = 0;
  u16* xns[3]; for (int c=0;c<3;c++) xns[c] = (u16*)aalloc((size_t)NN*128*2);
  float* topv = (float*)aalloc((size_t)NN*16*4);
  int*   topi = (int*)aalloc((size_t)NN*16*4);
  float* dg2of = (float*)aalloc((size_t)NN*192*4);
  size_t dyn0 = ac;

  const size_t sbytes = (size_t)NN*SCC*4;
  const bool paired = (dyn0 + 2*sbytes + 512) <= ARENA_SZ;

  auto dyn_layer = [&](int P, const float* xf,
                       const u16* xh, const u16* xm, const u16* xl, int lda, int ldal,
                       int Dx, int wi, float* ofp, int co, u16* lout, int H1, int H2, int nch){
    const int R = nch*KEDGE;   // mult of 128
    ac = dyn0;
    float* S0 = (float*)aalloc(sbytes);
    float* S1 = paired ? (float*)aalloc(sbytes) : nullptr;
    ac = dyn0;   // alias: S dead once topk loop finishes
    u16* mms[3]; for (int c=0;c<3;c++) mms[c] = (u16*)aalloc((size_t)R*H1*2);
    float* mout = (float*)aalloc((size_t)R*H2*4);

    k_normalize<<<NN, 64, 0, stream>>>(xf, xns[0], xns[1], xns[2], Dx);
    auto simg = [&](int cb, float* Sdst){
      MG(3, xns[0],xns[1],xns[2], Dx,Dx,
         xns[0]+(size_t)cb*Dx, xns[1]+(size_t)cb*Dx, xns[2]+(size_t)cb*Dx, Dx,
         Sdst, nullptr,nullptr,nullptr, SCC,0,0,0, NN, Dx, SCC, 1.0f, 2, cb);
    };
    if (paired){
      for (int cb = 0; cb < NN; cb += 2*SCC){
        simg(cb, S0);
        simg(cb + SCC, S1);
        k_topk_merge<<<NN/4, 256, 0, stream>>>(S0, S1, cb, topv, topi, cb == 0);
      }
    } else {
      for (int cb = 0; cb < NN; cb += SCC){
        simg(cb, S0);
        k_topk_merge<<<NN/4, 256, 0, stream>>>(S0, nullptr, cb, topv, topi, cb == 0);
      }
    }
    MG(P, xh,xm,xl, lda,ldal, wh[wi+2],wm[wi+2],wl[wi+2], Dx,
       ofp, nullptr,nullptr,nullptr, H2,0,0,0, NN, Dx, H2, 0.1f, 0, 0);   // ofp = lrelu(x@lin)
    for (int c0 = 0; c0 < NN; c0 += nch){
      MGG(P, xf, topi, c0, Dx, wh[wi],wm[wi],wl[wi], 2*Dx,
          mms[0],mms[1],(P==3?mms[2]:nullptr), H1,H1, R, H1, 0.2f);
      MG(P, mms[0],mms[1],mms[2], H1,H1, wh[wi+1],wm[wi+1],wl[wi+1], H1,
         mout, nullptr,nullptr,nullptr, H2,0,0,0, R, H1, H2, 0.2f, 0, 0);
      k_segmax_add<<<nch, H2, 0, stream>>>(mout, H2, c0, ofp);            // ofp += segmax
    }
    k_split3<<<(NN*H2+255)/256, 256, 0, stream>>>(ofp, cat1h, cat1m, lout,
                                                  NN*H2, H2, 704, co, H2);
  };
  dyn_layer(3, sg1f, cat1h+0, cat1m+0, sg1l, 704,64, 64,  12, dg1f, 64,  dg1l, 128, 128, 4096);
  dyn_layer(2, dg1f, cat1h+64,cat1m+64,nullptr,704,0, 128, 15, dg2of,192, nullptr,192, 192, 2048);

  // -------- fusion-phase arena --------
  ac = 0;
  u16*   f1sh = (u16*)aalloc((size_t)NN*1024*2);   // f1 splits [NN,1024]
  u16*   f1sm = (u16*)aalloc((size_t)NN*1024*2);
  float* fscr = (float*)aalloc((size_t)NN*512*4);  // fp32 scratch [NN,512]
  // aliases once producers are dead:
  u16* h2h = f1sh;
  u16* h2m = f1sm;
  float* h3f32 = (float*)(f1sm + (size_t)NN*512);
  u16* h3h = f1sh + (size_t)NN*512;
  u16* h3m = h3h + (size_t)NN*256;

  auto bn = [&](const float* X, int C, int Cshift, const float* g, const float* b,
                u16* Oh, u16* Om, int ldo, int co){
    k_bn_part<<<dim3(C/64, 32), 256, 0, stream>>>(X, C, bnp, bnp + 32*1024);
    k_bn_stats<<<(C+255)/256, 256, 0, stream>>>(bnp, bnp + 32*1024, C, bns);
    k_bn_apply<<<2048, 256, 0, stream>>>(X, Cshift, C, bns, g, b, Oh, Om, ldo, co, NN*C);
  };

  // f1 in two 512-col halves: fscr = cat1 @ f1_w[:, p*512:...] ; bn -> f1s
  for (int p = 0; p < 2; p++){
    MG(2, cat1h,cat1m,nullptr, 704,0, wh[18]+(size_t)p*512*704, wm[18]+(size_t)p*512*704, nullptr, 704,
       fscr, nullptr,nullptr,nullptr, 512,0,0,0, NN, 704, 512, 1.f, 0, 0);
    bn(fscr, 512, 9, f1_g + p*512, f1_b + p*512, f1sh, f1sm, 1024, p*512);
  }
  // h2 = lrelu(bn(cat2 @ f2_w1)) ; cat2 = [f1 | cat1]
  MG(2, f1sh,f1sm,nullptr, 1024,0, wh[19],wm[19],nullptr, 1728,
     fscr, nullptr,nullptr,nullptr, 512,0,0,0, NN, 1024, 512, 1.f, 0, 0);
  MG(2, cat1h,cat1m,nullptr, 704,0, wh[19]+1024,wm[19]+1024,nullptr, 1728,
     fscr, nullptr,nullptr,nullptr, 512,0,0,0, NN, 704, 512, 1.f, 1, 0);
  bn(fscr, 512, 9, f2_g1, f2_b1, h2h, h2m, 512, 0);
  MG(2, h2h,h2m,nullptr, 512,0, wh[20],wm[20],nullptr, 512,
     h3f32, nullptr,nullptr,nullptr, 256,0,0,0, NN, 512, 256, 1.f, 0, 0);
  bn(h3f32, 256, 8, f2_g2, f2_b2, h3h, h3m, 256, 0);
  MG(2, h3h,h3m,nullptr, 256,0, wh[21],wm[21],nullptr, 256,
     out, nullptr,nullptr,nullptr, 128,0,0,0, NN, 256, 128, 1.f, 0, 0);
}